// Round 14
// baseline (517.033 us; speedup 1.0000x reference)
//
#include <hip/hip_runtime.h>
#include <math.h>

#define B_TOK 4096
#define D_DIM 1024
#define H_DIM 2048
#define O_DIM 1024
#define E_NUM 16
#define K_TOP 4

#define TBM 256
#define TBN 256
#define TBK 32

typedef __attribute__((ext_vector_type(4))) float f32x4;
typedef __attribute__((ext_vector_type(8))) short bf16x8;
typedef __attribute__((ext_vector_type(4))) unsigned short u16x4;

__device__ __forceinline__ unsigned short f2b(float f) {
  unsigned u = __builtin_bit_cast(unsigned, f);
  u = u + 0x7FFFu + ((u >> 16) & 1u);
  return (unsigned short)(u >> 16);
}
__device__ __forceinline__ float b2f(unsigned short s) {
  return __builtin_bit_cast(float, ((unsigned)s) << 16);
}
__device__ __forceinline__ void async_load16(const unsigned short* g, unsigned short* l) {
  __builtin_amdgcn_global_load_lds(
      (const __attribute__((address_space(1))) unsigned int*)g,
      (__attribute__((address_space(3))) unsigned int*)l, 16, 0, 0);
}

// ------------------------------------------- gating + x->bf16 (body) --------
__device__ __forceinline__ void gating_body(
    int b, const float* __restrict__ x, const float* __restrict__ noise,
    const float* __restrict__ w_gate, const float* __restrict__ w_noise,
    int* __restrict__ counts, int* __restrict__ pair_v,
    float* __restrict__ gate_bk, float* __restrict__ gates_full,
    float* __restrict__ prob_ws, unsigned short* __restrict__ xb)
{
  const int t = threadIdx.x;
  const int e = t & 15, seg = t >> 4;           // 16 segs x 64 d each
  const float* __restrict__ xr = x + (size_t)b * D_DIM;

  float pg = 0.f, pn = 0.f;
  #pragma unroll 8
  for (int j = 0; j < 64; ++j) {
    const int d = seg * 64 + j;
    const float xv = xr[d];
    pg += xv * w_gate[d * E_NUM + e];
    pn += xv * w_noise[d * E_NUM + e];
  }
  // fused x -> bf16 (row is L1/L2-hot): thread t covers elems 4t..4t+3
  {
    const f32x4 xv4 = *(const f32x4*)&xr[t * 4];
    u16x4 o;
    o[0] = f2b(xv4[0]); o[1] = f2b(xv4[1]);
    o[2] = f2b(xv4[2]); o[3] = f2b(xv4[3]);
    *(u16x4*)&xb[(size_t)b * D_DIM + t * 4] = o;
  }
  __shared__ float sg[16][16], sn[16][16];
  sg[seg][e] = pg; sn[seg][e] = pn;
  __syncthreads();

  __shared__ float s_clean[16], s_std[16], s_noisy[16];
  if (t < 32) {
    const int which = t >> 4, ee = t & 15;
    float s = 0.f;
    #pragma unroll
    for (int i = 0; i < 16; ++i) s += which ? sn[i][ee] : sg[i][ee];
    if (which == 0) s_clean[ee] = s;
    else {
      const float sp = (s > 0.f) ? (s + log1pf(expf(-s))) : log1pf(expf(s));
      s_std[ee] = sp + 0.01f;
    }
  }
  __syncthreads();
  if (t < 16) s_noisy[t] = s_clean[t] + noise[(size_t)b * E_NUM + t] * s_std[t];
  __syncthreads();

  __shared__ float s_top[5];
  __shared__ int   s_idx[4];
  __shared__ float s_gates[4];
  if (t == 0) {
    float v[16];
    #pragma unroll
    for (int i = 0; i < 16; ++i) v[i] = s_noisy[i];
    unsigned mask = 0;
    float tv[5]; int ti[5];
    #pragma unroll
    for (int k = 0; k < 5; ++k) {
      float best = -3.4e38f; int bi = 0;
      #pragma unroll
      for (int i = 0; i < 16; ++i) {
        const bool ok = !((mask >> i) & 1u) && (v[i] > best);
        best = ok ? v[i] : best;
        bi   = ok ? i    : bi;
      }
      mask |= (1u << bi);
      tv[k] = best; ti[k] = bi;
    }
    const float m = tv[0];
    float ex[4], se = 0.f;
    #pragma unroll
    for (int k = 0; k < 4; ++k) { ex[k] = expf(tv[k] - m); se += ex[k]; }
    #pragma unroll
    for (int k = 0; k < 4; ++k) s_gates[k] = ex[k] / se;
    #pragma unroll
    for (int k = 0; k < 5; ++k) s_top[k] = tv[k];
    #pragma unroll
    for (int k = 0; k < 4; ++k) s_idx[k] = ti[k];
  }
  __syncthreads();

  if (t < 16) gates_full[(size_t)b * E_NUM + t] = 0.f;
  __syncthreads();
  if (t < 4) {
    const int ee = s_idx[t];
    const float g = s_gates[t];
    gate_bk[b * K_TOP + t] = g;
    gates_full[(size_t)b * E_NUM + ee] = g;
    const int slot = atomicAdd(&counts[ee], 1);
    pair_v[ee * B_TOK + slot] = b * K_TOP + t;     // h-row index = b*4 + rank
  }
  if (t < 16) {
    const float thr_in = s_top[4], thr_out = s_top[3];
    const float thr = (s_noisy[t] > thr_in) ? thr_in : thr_out;
    const float z = (s_clean[t] - thr) / s_std[t];
    prob_ws[(size_t)b * E_NUM + t] = 0.5f * (1.f + erff(z * 0.70710678118654752f));
  }
}

// ------------------- direct transpose fp32->bf16, 128B-per-lane writes ------
// in[e][R][C] fp32 -> out[e][C][R] bf16.  Lane owns output row n and 64
// consecutive k.  sched_barrier(0) forces ALL 64 strided loads to issue
// before any convert/store -> MLP=64.
__device__ __forceinline__ void transpose64(
    const float* __restrict__ in, unsigned short* __restrict__ out,
    int R, int C, int e, int n, int k0)
{
  const float* __restrict__ ip = in + (size_t)e * R * C + (size_t)k0 * C + n;
  unsigned short* __restrict__ op = out + (size_t)e * R * C + (size_t)n * R + k0;
  float v[64];
  #pragma unroll
  for (int q = 0; q < 64; ++q) v[q] = ip[(size_t)q * C];
  __builtin_amdgcn_sched_barrier(0);        // issue all 64 loads first
  #pragma unroll
  for (int h8 = 0; h8 < 8; ++h8) {
    bf16x8 o;
    #pragma unroll
    for (int q = 0; q < 8; ++q) o[q] = (short)f2b(v[h8 * 8 + q]);
    *(bf16x8*)&op[h8 * 8] = o;
  }
}

// --------------------------------------------------------------- mega K1 ----
// gating+convert (4096) | T1: W1->Wt1 (2048 blocks, 64n x 256k tiles)
__global__ __launch_bounds__(256) void mega1_kernel(
    const float* __restrict__ x, const float* __restrict__ noise,
    const float* __restrict__ w_gate, const float* __restrict__ w_noise,
    int* __restrict__ counts, int* __restrict__ pair_v,
    float* __restrict__ gate_bk, float* __restrict__ gates_full,
    float* __restrict__ prob_ws, unsigned short* __restrict__ xb,
    const float* __restrict__ W1, unsigned short* __restrict__ Wt1)
{
  int bid = blockIdx.x;
  if (bid < B_TOK) {
    gating_body(bid, x, noise, w_gate, w_noise, counts, pair_v,
                gate_bk, gates_full, prob_ws, xb);
    return;
  }
  bid -= B_TOK;      // T1: R=D(k)=1024, C=H(n)=2048: nb 32 x kb 4 x e 16
  const int nb = bid & 31, kb = (bid >> 5) & 3, e = bid >> 7;
  const int w = threadIdx.x >> 6, lane = threadIdx.x & 63;
  transpose64(W1, Wt1, D_DIM, H_DIM, e, nb * 64 + lane, kb * 256 + w * 64);
}

// standalone T2 (fallback path, between gemms): grid (16 nb, 8 kb, 16 e)
__global__ __launch_bounds__(256) void transpose_dir_kernel(
    const float* __restrict__ in, unsigned short* __restrict__ out,
    int R, int C)
{
  const int w = threadIdx.x >> 6, lane = threadIdx.x & 63;
  transpose64(in, out, R, C, blockIdx.z, blockIdx.x * 64 + lane,
              blockIdx.y * 256 + w * 64);
}

// -------------------------------------------------------------- prep tasks --
// Per-XCD queues; experts {x, x+8} -> XCD x.  Order (e, nb, m).
__global__ void prep_tasks_kernel(const int* __restrict__ counts,
                                  int* __restrict__ tasks1,   // [8][256]
                                  int* __restrict__ tasks2,   // [8][128]
                                  int* __restrict__ meta)     // n1[8], n2[8]
{
  const int xx = threadIdx.x;
  if (xx < 8) {
    int k1 = 0, k2 = 0;
    for (int hh = 0; hh < 2; ++hh) {
      const int e = xx + hh * 8;
      const int mb = (counts[e] + TBM - 1) / TBM;
      for (int nb = 0; nb < H_DIM / TBN; ++nb)
        for (int m = 0; m < mb; ++m)
          tasks1[xx * 256 + (k1++)] = (e << 16) | (m << 8) | nb;
      for (int nb = 0; nb < O_DIM / TBN; ++nb)
        for (int m = 0; m < mb; ++m)
          tasks2[xx * 128 + (k2++)] = (e << 16) | (m << 8) | nb;
    }
    meta[xx] = k1;
    meta[8 + xx] = k2;
  }
}

// -- GEMM 256x256, TBK=32, 2 blocks/CU (66KB LDS), per-XCD + steal; T2 co ----
// 512 thr = 8 waves (2 wr x 4 wc), 128x64 out/wave.  LDS = 2buf x 16KB x 2
// operands = 64KB -> 2 blocks/CU: co-resident block's MFMA covers this
// block's vmcnt drain (m114; R8 measured 4.3 TB/s staging at >1 block/CU).
// Swizzle (4 chunks/row): chunk c of row r holds global chunk c^(r&3)
// (involution; issue-invariant since 128%4==0); read chunk gA^(ra&3).
template<int NDIM, int KDIM, bool RELU, bool APAIR, int QSTRIDE>
__global__ __launch_bounds__(512, 1) void gemm256ws_kernel(
    const unsigned short* __restrict__ A,
    const unsigned short* __restrict__ Bt,
    const float* __restrict__ biasE,
    const int* __restrict__ counts, const int* __restrict__ pair_v,
    const int* __restrict__ tasks,     // [8][QSTRIDE]
    const int* __restrict__ ntasks,    // [8]
    int* __restrict__ xctr,            // [8]
    unsigned short* __restrict__ Out,
    const float* __restrict__ T2src, unsigned short* __restrict__ T2dst,
    int ngemm)
{
  const int t = threadIdx.x;
  const int w = t >> 6, l = t & 63;

  if ((int)blockIdx.x >= ngemm) {   // T2: R=H(k)=2048, C=O(n)=1024
    const int idx = (int)blockIdx.x - ngemm;   // nb 16 x kb 4 x e 16
    const int nb = idx & 15, kb = (idx >> 4) & 3, e2 = idx >> 6;
    transpose64(T2src, T2dst, H_DIM, O_DIM, e2, nb * 64 + l, kb * 512 + w * 64);
    return;
  }

  __shared__ __align__(16) unsigned short As[2][TBM * TBK];   // 2 x 16 KB
  __shared__ __align__(16) unsigned short Bs[2][TBN * TBK];   // 2 x 16 KB
  __shared__ int s_task;

  const int xcd = blockIdx.x & 7;

  // staging: slot s = i2*512 + t ; row r = s>>2 = i2*128 + (t>>2), chunk
  // c = t&3 ; LDS elem = s*8 (linear). Global chunk gc = c ^ (r&3)
  // = (t&3) ^ ((t>>2)&3)  (issue-invariant, 128%4==0).
  const int gc = (t & 3) ^ ((t >> 2) & 3);
  const int sr = t >> 2;                    // 0..127

  const int wr = w >> 2, wc = w & 3;
  const int lr = l & 15, gA = l >> 4;       // gA in 0..3 (chunk index)

  for (int v = 0; v < 8; ++v) {             // home queue, then steal
    const int q = (xcd + v) & 7;
    const int nt = ntasks[q];
    const int* __restrict__ tl = tasks + q * QSTRIDE;
    for (;;) {
      if (t == 0) s_task = atomicAdd(&xctr[q], 1);
      __syncthreads();                      // publish + prev-task drain
      const int task = s_task;
      if (task >= nt) break;

      const int tk = tl[task];
      const int e  = tk >> 16;
      const int m0 = ((tk >> 8) & 255) * TBM;
      const int n0 = (tk & 255) * TBN;
      const int cnt = counts[e];
      const int* __restrict__ plist = pair_v + e * B_TOK;

      const unsigned short* aG[2];
      const unsigned short* bG[2];
      #pragma unroll
      for (int i2 = 0; i2 < 2; ++i2) {
        const int r = i2 * 128 + sr;
        const int pr = (m0 + r < cnt) ? plist[m0 + r] : -1;
        const size_t tok = (size_t)(pr < 0 ? 0 : (APAIR ? pr : (pr >> 2)));
        aG[i2] = A + tok * KDIM + gc * 8;
        bG[i2] = Bt + ((size_t)e * NDIM + n0 + r) * KDIM + gc * 8;
      }

#define STAGE(bufi, kt) do {                                   \
    const int ko_ = (kt) * TBK;                                \
    async_load16(aG[0] + ko_, &As[bufi][w * 512]);             \
    async_load16(aG[1] + ko_, &As[bufi][4096 + w * 512]);      \
    async_load16(bG[0] + ko_, &Bs[bufi][w * 512]);             \
    async_load16(bG[1] + ko_, &Bs[bufi][4096 + w * 512]);      \
  } while (0)

      f32x4 acc[8][4];
      #pragma unroll
      for (int i = 0; i < 8; ++i)
        #pragma unroll
        for (int j = 0; j < 4; ++j)
          acc[i][j] = (f32x4){0.f, 0.f, 0.f, 0.f};

      STAGE(0, 0);
      __syncthreads();                      // drains vmcnt(0): buf0 ready

      int buf = 0;
      constexpr int KIT = KDIM / TBK;       // 32 or 64
      for (int kt = 0; kt < KIT; ++kt) {
        if (kt + 1 < KIT) STAGE(buf ^ 1, kt + 1);
        bf16x8 a[8], bv[4];
        #pragma unroll
        for (int i = 0; i < 8; ++i) {
          const int ra = wr * 128 + i * 16 + lr;
          a[i] = *(const bf16x8*)&As[buf][ra * 32 + ((gA ^ (ra & 3)) << 3)];
        }
        #pragma unroll
        for (int j = 0; j < 4; ++j) {
          const int rb = wc * 64 + j * 16 + lr;
          bv[j] = *(const bf16x8*)&Bs[buf][rb * 32 + ((gA ^ (rb & 3)) << 3)];
        }
        #pragma unroll
        for (int i = 0; i < 8; ++i)
          #pragma unroll
          for (int j = 0; j < 4; ++j)
            acc[i][j] = __builtin_amdgcn_mfma_f32_16x16x32_bf16(a[i], bv[j], acc[i][j], 0, 0, 0);
        __syncthreads();                    // waits vmcnt(0): next buf landed
        buf ^= 1;
      }
#undef STAGE

      const float* __restrict__ bias = biasE + (size_t)e * NDIM + n0;
      #pragma unroll
      for (int i = 0; i < 8; ++i) {
        #pragma unroll
        for (int q2 = 0; q2 < 4; ++q2) {
          const int rl = wr * 128 + i * 16 + gA * 4 + q2;
          if (m0 + rl < cnt) {
            const int pr = plist[m0 + rl];
            #pragma unroll
            for (int j = 0; j < 4; ++j) {
              const int col = wc * 64 + j * 16 + lr;
              float vv = acc[i][j][q2] + bias[col];
              if (RELU) vv = vv > 0.f ? vv : 0.f;
              Out[(size_t)pr * NDIM + n0 + col] = f2b(vv);
            }
          }
        }
      }
    }
  }
}

// ------------------------------------------------------- softmax+y (body) ---
__device__ __forceinline__ void softmax_body(
    int b, const unsigned short* __restrict__ outw,
    const float* __restrict__ gate_bk, float* __restrict__ y)
{
  const int t = threadIdx.x;
  const int w = t >> 6, l = t & 63;
  __shared__ float acc_s[4][O_DIM];

  const unsigned short* __restrict__ row = outw + (size_t)(b * K_TOP + w) * O_DIM;
  float v[16];
  const bf16x8 r0 = *(const bf16x8*)&row[l * 16];
  const bf16x8 r1 = *(const bf16x8*)&row[l * 16 + 8];
  #pragma unroll
  for (int i = 0; i < 8; ++i) {
    v[i]     = b2f((unsigned short)r0[i]);
    v[i + 8] = b2f((unsigned short)r1[i]);
  }
  float mx = v[0];
  #pragma unroll
  for (int i = 1; i < 16; ++i) mx = fmaxf(mx, v[i]);
  #pragma unroll
  for (int off = 32; off >= 1; off >>= 1) mx = fmaxf(mx, __shfl_xor(mx, off, 64));
  float ex[16], ps = 0.f;
  #pragma unroll
  for (int i = 0; i < 16; ++i) { ex[i] = expf(v[i] - mx); ps += ex[i]; }
  #pragma unroll
  for (int off = 32; off >= 1; off >>= 1) ps += __shfl_xor(ps, off, 64);
  const float g = gate_bk[b * K_TOP + w];
  const float inv = 1.f / ps;
  #pragma unroll
  for (int i = 0; i < 16; ++i) acc_s[w][l * 16 + i] = g * expf(ex[i] * inv);
  __syncthreads();
  #pragma unroll
  for (int i = 0; i < 4; ++i) {
    const int col = t + i * 256;
    y[(size_t)b * O_DIM + col] =
        acc_s[0][col] + acc_s[1][col] + acc_s[2][col] + acc_s[3][col];
  }
}

// ------------------------------------------------------- loss part (body) ---
__device__ __forceinline__ void losspart_body(
    int blk, const float* __restrict__ gates_full,
    const float* __restrict__ prob_ws, float* __restrict__ part)
{
  const int t = threadIdx.x;
  const int e = t & 15, seg = t >> 4;
  float si = 0.f, sl = 0.f;
  #pragma unroll
  for (int j = 0; j < 4; ++j) {
    const int b = blk * 64 + seg * 4 + j;
    si += gates_full[(size_t)b * E_NUM + e];
    sl += prob_ws[(size_t)b * E_NUM + e];
  }
  __shared__ float li[16][16], ll[16][16];
  li[seg][e] = si; ll[seg][e] = sl;
  __syncthreads();
  if (t < 32) {
    const int which = t >> 4, ee = t & 15;
    float s = 0.f;
    #pragma unroll
    for (int i = 0; i < 16; ++i) s += which ? ll[i][ee] : li[i][ee];
    part[(blk * 2 + which) * 16 + ee] = s;
  }
}

// --------------------------------------------------------------- mega K4 ----
__global__ __launch_bounds__(256) void mega2_kernel(
    const unsigned short* __restrict__ outw, const float* __restrict__ gate_bk,
    float* __restrict__ y, const float* __restrict__ gates_full,
    const float* __restrict__ prob_ws, float* __restrict__ part)
{
  const int bid = blockIdx.x;
  if (bid < B_TOK) softmax_body(bid, outw, gate_bk, y);
  else             losspart_body(bid - B_TOK, gates_full, prob_ws, part);
}

__global__ __launch_bounds__(64) void loss_final_kernel(
    const float* __restrict__ part, float* __restrict__ out_loss)
{
  const int t = threadIdx.x;
  __shared__ float fi[16], fl[16];
  if (t < 32) {
    const int which = t >> 4, e = t & 15;
    float s = 0.f;
    for (int i = 0; i < 64; ++i) s += part[(i * 2 + which) * 16 + e];
    if (which) fl[e] = s; else fi[e] = s;
  }
  __syncthreads();
  if (t == 0) {
    float mi = 0.f, ml = 0.f;
    #pragma unroll
    for (int e = 0; e < 16; ++e) { mi += fi[e]; ml += fl[e]; }
    mi *= (1.f / 16.f); ml *= (1.f / 16.f);
    float vi = 0.f, vl = 0.f;
    #pragma unroll
    for (int e = 0; e < 16; ++e) {
      const float di = fi[e] - mi, dl = fl[e] - ml;
      vi += di * di; vl += dl * dl;
    }
    vi *= (1.f / 15.f); vl *= (1.f / 15.f);
    out_loss[0] = (vi / (mi * mi + 1e-10f) + vl / (ml * ml + 1e-10f)) * 0.01f;
  }
}

// ---------------------------------------------------------------- launch ----
extern "C" void kernel_launch(void* const* d_in, const int* in_sizes, int n_in,
                              void* d_out, int out_size, void* d_ws, size_t ws_size,
                              hipStream_t stream)
{
  (void)in_sizes; (void)n_in; (void)out_size;
  const float* x       = (const float*)d_in[0];
  const float* noise   = (const float*)d_in[1];
  const float* w_gate  = (const float*)d_in[2];
  const float* w_noise = (const float*)d_in[3];
  const float* W1      = (const float*)d_in[4];
  const float* b1      = (const float*)d_in[5];
  const float* W2      = (const float*)d_in[6];
  const float* b2      = (const float*)d_in[7];
  float* out = (float*)d_out;

  char* wsc = (char*)d_ws;
  int*   counts     = (int*)wsc;                          // 16
  int*   xctr       = counts + 16;                        // 16 (8 per gemm)
  int*   meta       = xctr + 16;                          // 16 (n1[8], n2[8])
  int*   tasks1     = meta + 16;                          // 8*256
  int*   tasks2     = tasks1 + 8 * 256;                   // 8*128
  int*   pair_v     = tasks2 + 8 * 128;                   // E*B
  float* gate_bk    = (float*)(pair_v + E_NUM * B_TOK);   // B*K
  float* gates_full = gate_bk + B_TOK * K_TOP;            // B*E
  float* prob_ws    = gates_full + B_TOK * E_NUM;         // B*E
  float* part       = prob_ws + B_TOK * E_NUM;            // 64*2*16
  char* big = wsc + ((((char*)(part + 64 * 2 * 16) - wsc) + 255) & ~255);
  unsigned short* x_bf = (unsigned short*)big;                         // 8.4 MB
  unsigned short* Wt1  = x_bf + (size_t)B_TOK * D_DIM;                 // 67 MB
  unsigned short* h    = Wt1 + (size_t)E_NUM * D_DIM * H_DIM;          // 67 MB
  unsigned short* outw = h + (size_t)B_TOK * K_TOP * H_DIM;            // 34 MB
  unsigned short* wt2_sep = outw + (size_t)B_TOK * K_TOP * O_DIM;      // 67 MB (opt)

  const size_t need_big =
      (size_t)((char*)(wt2_sep + (size_t)E_NUM * H_DIM * O_DIM) - wsc);
  const int bigws = (ws_size >= need_big) ? 1 : 0;
  unsigned short* Wt2 = bigws ? wt2_sep : Wt1;

  hipMemsetAsync(counts, 0, 48 * sizeof(int), stream);    // counts + xctr + meta

  // K1: gating+convert | T1 (128B-per-lane write transpose, MLP=64)
  mega1_kernel<<<B_TOK + 2048, 256, 0, stream>>>(
      x, noise, w_gate, w_noise, counts, pair_v, gate_bk, gates_full, prob_ws,
      x_bf, W1, Wt1);

  prep_tasks_kernel<<<1, 64, 0, stream>>>(counts, tasks1, tasks2, meta);

  // gemm1 (512 blocks = 2/CU) + T2 hidden underneath if bigws
  gemm256ws_kernel<H_DIM, D_DIM, true, false, 256>
      <<<512 + (bigws ? 1024 : 0), 512, 0, stream>>>(
      x_bf, Wt1, b1, counts, pair_v, tasks1, meta, xctr, h, W2, Wt2, 512);

  if (!bigws) {   // fallback: transpose W2 into Wt1 between the gemms
    transpose_dir_kernel<<<dim3(O_DIM / 64, H_DIM / 256, E_NUM), 256, 0, stream>>>(
        W2, Wt1, H_DIM, O_DIM);
  }

  gemm256ws_kernel<O_DIM, H_DIM, false, true, 128><<<512, 512, 0, stream>>>(
      h, Wt2, b2, counts, pair_v, tasks2, meta + 8, xctr + 8, outw,
      (const float*)nullptr, (unsigned short*)nullptr, 512);

  // K4: softmax_y | loss partials
  mega2_kernel<<<B_TOK + 64, 256, 0, stream>>>(outw, gate_bk, out,
                                               gates_full, prob_ws, part);
  loss_final_kernel<<<1, 64, 0, stream>>>(part, out + (size_t)B_TOK * O_DIM);
}

// Round 15
// 510.324 us; speedup vs baseline: 1.0131x; 1.0131x over previous
//
#include <hip/hip_runtime.h>
#include <math.h>

#define B_TOK 4096
#define D_DIM 1024
#define H_DIM 2048
#define O_DIM 1024
#define E_NUM 16
#define K_TOP 4

#define TBM 256
#define TBN 256
#define TBK 32

typedef __attribute__((ext_vector_type(4))) float f32x4;
typedef __attribute__((ext_vector_type(8))) short bf16x8;
typedef __attribute__((ext_vector_type(4))) unsigned short u16x4;

__device__ __forceinline__ unsigned short f2b(float f) {
  unsigned u = __builtin_bit_cast(unsigned, f);
  u = u + 0x7FFFu + ((u >> 16) & 1u);
  return (unsigned short)(u >> 16);
}
__device__ __forceinline__ float b2f(unsigned short s) {
  return __builtin_bit_cast(float, ((unsigned)s) << 16);
}
__device__ __forceinline__ void async_load16(const unsigned short* g, unsigned short* l) {
  __builtin_amdgcn_global_load_lds(
      (const __attribute__((address_space(1))) unsigned int*)g,
      (__attribute__((address_space(3))) unsigned int*)l, 16, 0, 0);
}

// ------------------------------------------- gating + x->bf16 (body) --------
__device__ __forceinline__ void gating_body(
    int b, const float* __restrict__ x, const float* __restrict__ noise,
    const float* __restrict__ w_gate, const float* __restrict__ w_noise,
    int* __restrict__ counts, int* __restrict__ pair_v,
    float* __restrict__ gate_bk, float* __restrict__ gates_full,
    float* __restrict__ prob_ws, unsigned short* __restrict__ xb)
{
  const int t = threadIdx.x;
  const int e = t & 15, seg = t >> 4;           // 16 segs x 64 d each
  const float* __restrict__ xr = x + (size_t)b * D_DIM;

  float pg = 0.f, pn = 0.f;
  #pragma unroll 8
  for (int j = 0; j < 64; ++j) {
    const int d = seg * 64 + j;
    const float xv = xr[d];
    pg += xv * w_gate[d * E_NUM + e];
    pn += xv * w_noise[d * E_NUM + e];
  }
  // fused x -> bf16 (row is L1/L2-hot): thread t covers elems 4t..4t+3
  {
    const f32x4 xv4 = *(const f32x4*)&xr[t * 4];
    u16x4 o;
    o[0] = f2b(xv4[0]); o[1] = f2b(xv4[1]);
    o[2] = f2b(xv4[2]); o[3] = f2b(xv4[3]);
    *(u16x4*)&xb[(size_t)b * D_DIM + t * 4] = o;
  }
  __shared__ float sg[16][16], sn[16][16];
  sg[seg][e] = pg; sn[seg][e] = pn;
  __syncthreads();

  __shared__ float s_clean[16], s_std[16], s_noisy[16];
  if (t < 32) {
    const int which = t >> 4, ee = t & 15;
    float s = 0.f;
    #pragma unroll
    for (int i = 0; i < 16; ++i) s += which ? sn[i][ee] : sg[i][ee];
    if (which == 0) s_clean[ee] = s;
    else {
      const float sp = (s > 0.f) ? (s + log1pf(expf(-s))) : log1pf(expf(s));
      s_std[ee] = sp + 0.01f;
    }
  }
  __syncthreads();
  if (t < 16) s_noisy[t] = s_clean[t] + noise[(size_t)b * E_NUM + t] * s_std[t];
  __syncthreads();

  __shared__ float s_top[5];
  __shared__ int   s_idx[4];
  __shared__ float s_gates[4];
  if (t == 0) {
    float v[16];
    #pragma unroll
    for (int i = 0; i < 16; ++i) v[i] = s_noisy[i];
    unsigned mask = 0;
    float tv[5]; int ti[5];
    #pragma unroll
    for (int k = 0; k < 5; ++k) {
      float best = -3.4e38f; int bi = 0;
      #pragma unroll
      for (int i = 0; i < 16; ++i) {
        const bool ok = !((mask >> i) & 1u) && (v[i] > best);
        best = ok ? v[i] : best;
        bi   = ok ? i    : bi;
      }
      mask |= (1u << bi);
      tv[k] = best; ti[k] = bi;
    }
    const float m = tv[0];
    float ex[4], se = 0.f;
    #pragma unroll
    for (int k = 0; k < 4; ++k) { ex[k] = expf(tv[k] - m); se += ex[k]; }
    #pragma unroll
    for (int k = 0; k < 4; ++k) s_gates[k] = ex[k] / se;
    #pragma unroll
    for (int k = 0; k < 5; ++k) s_top[k] = tv[k];
    #pragma unroll
    for (int k = 0; k < 4; ++k) s_idx[k] = ti[k];
  }
  __syncthreads();

  if (t < 16) gates_full[(size_t)b * E_NUM + t] = 0.f;
  __syncthreads();
  if (t < 4) {
    const int ee = s_idx[t];
    const float g = s_gates[t];
    gate_bk[b * K_TOP + t] = g;
    gates_full[(size_t)b * E_NUM + ee] = g;
    const int slot = atomicAdd(&counts[ee], 1);
    pair_v[ee * B_TOK + slot] = b * K_TOP + t;     // h-row index = b*4 + rank
  }
  if (t < 16) {
    const float thr_in = s_top[4], thr_out = s_top[3];
    const float thr = (s_noisy[t] > thr_in) ? thr_in : thr_out;
    const float z = (s_clean[t] - thr) / s_std[t];
    prob_ws[(size_t)b * E_NUM + t] = 0.5f * (1.f + erff(z * 0.70710678118654752f));
  }
}

// ------------------- direct transpose fp32->bf16, 128B-per-lane writes ------
// in[e][R][C] fp32 -> out[e][C][R] bf16.  Lane owns output row n and 64
// consecutive k.  sched_barrier(0) forces ALL 64 strided loads to issue
// before any convert/store -> MLP=64.
__device__ __forceinline__ void transpose64(
    const float* __restrict__ in, unsigned short* __restrict__ out,
    int R, int C, int e, int n, int k0)
{
  const float* __restrict__ ip = in + (size_t)e * R * C + (size_t)k0 * C + n;
  unsigned short* __restrict__ op = out + (size_t)e * R * C + (size_t)n * R + k0;
  float v[64];
  #pragma unroll
  for (int q = 0; q < 64; ++q) v[q] = ip[(size_t)q * C];
  __builtin_amdgcn_sched_barrier(0);        // issue all 64 loads first
  #pragma unroll
  for (int h8 = 0; h8 < 8; ++h8) {
    bf16x8 o;
    #pragma unroll
    for (int q = 0; q < 8; ++q) o[q] = (short)f2b(v[h8 * 8 + q]);
    *(bf16x8*)&op[h8 * 8] = o;
  }
}

// --------------------------------------------------------------- mega K1 ----
// gating+convert (4096) | T1: W1->Wt1 (2048 blocks, 64n x 256k tiles)
__global__ __launch_bounds__(256) void mega1_kernel(
    const float* __restrict__ x, const float* __restrict__ noise,
    const float* __restrict__ w_gate, const float* __restrict__ w_noise,
    int* __restrict__ counts, int* __restrict__ pair_v,
    float* __restrict__ gate_bk, float* __restrict__ gates_full,
    float* __restrict__ prob_ws, unsigned short* __restrict__ xb,
    const float* __restrict__ W1, unsigned short* __restrict__ Wt1)
{
  int bid = blockIdx.x;
  if (bid < B_TOK) {
    gating_body(bid, x, noise, w_gate, w_noise, counts, pair_v,
                gate_bk, gates_full, prob_ws, xb);
    return;
  }
  bid -= B_TOK;      // T1: R=D(k)=1024, C=H(n)=2048: nb 32 x kb 4 x e 16
  const int nb = bid & 31, kb = (bid >> 5) & 3, e = bid >> 7;
  const int w = threadIdx.x >> 6, lane = threadIdx.x & 63;
  transpose64(W1, Wt1, D_DIM, H_DIM, e, nb * 64 + lane, kb * 256 + w * 64);
}

// standalone T2 (fallback path, between gemms): grid (16 nb, 8 kb, 16 e)
__global__ __launch_bounds__(256) void transpose_dir_kernel(
    const float* __restrict__ in, unsigned short* __restrict__ out,
    int R, int C)
{
  const int w = threadIdx.x >> 6, lane = threadIdx.x & 63;
  transpose64(in, out, R, C, blockIdx.z, blockIdx.x * 64 + lane,
              blockIdx.y * 256 + w * 64);
}

// -------------------------------------------------------------- prep tasks --
// Per-XCD queues; experts {x, x+8} -> XCD x.  Order (e, nb, m).
__global__ void prep_tasks_kernel(const int* __restrict__ counts,
                                  int* __restrict__ tasks1,   // [8][256]
                                  int* __restrict__ tasks2,   // [8][128]
                                  int* __restrict__ meta)     // n1[8], n2[8]
{
  const int xx = threadIdx.x;
  if (xx < 8) {
    int k1 = 0, k2 = 0;
    for (int hh = 0; hh < 2; ++hh) {
      const int e = xx + hh * 8;
      const int mb = (counts[e] + TBM - 1) / TBM;
      for (int nb = 0; nb < H_DIM / TBN; ++nb)
        for (int m = 0; m < mb; ++m)
          tasks1[xx * 256 + (k1++)] = (e << 16) | (m << 8) | nb;
      for (int nb = 0; nb < O_DIM / TBN; ++nb)
        for (int m = 0; m < mb; ++m)
          tasks2[xx * 128 + (k2++)] = (e << 16) | (m << 8) | nb;
    }
    meta[xx] = k1;
    meta[8 + xx] = k2;
  }
}

// -- GEMM 256x256, TBK=32, 2 blocks/CU (64KB LDS), R7-verified swizzle -------
// 512 thr = 8 waves (2 wr x 4 wc), 128x64 out/wave.
// LDS per operand: [2 buf][256 rows][32 cols] bf16 = 32KB; 64KB total ->
// 2 blocks/CU: co-resident block's MFMA covers this block's vmcnt drain
// (m114; R8 measured 4.3 TB/s staging at >1 block/CU).
// Swizzle (R7-verified, 0 conflicts): chunk c of row r holds global chunk
// c ^ ((r>>1)&3); read chunk = gA ^ ((ra>>1)&3).  Bank math: row = 64B, bank
// = 16·ra + 4·chunk mod 32; (ra>>1)-keyed chunk cycles all 4 chunks per
// 8-row window -> exactly 2 lanes/bank (free, m136).
template<int NDIM, int KDIM, bool RELU, bool APAIR, int QSTRIDE>
__global__ __launch_bounds__(512, 1) void gemm256ws_kernel(
    const unsigned short* __restrict__ A,
    const unsigned short* __restrict__ Bt,
    const float* __restrict__ biasE,
    const int* __restrict__ counts, const int* __restrict__ pair_v,
    const int* __restrict__ tasks,     // [8][QSTRIDE]
    const int* __restrict__ ntasks,    // [8]
    int* __restrict__ xctr,            // [8]
    unsigned short* __restrict__ Out,
    const float* __restrict__ T2src, unsigned short* __restrict__ T2dst,
    int ngemm)
{
  const int t = threadIdx.x;
  const int w = t >> 6, l = t & 63;

  if ((int)blockIdx.x >= ngemm) {   // T2: R=H(k)=2048, C=O(n)=1024
    const int idx = (int)blockIdx.x - ngemm;   // nb 16 x kb 4 x e 16
    const int nb = idx & 15, kb = (idx >> 4) & 3, e2 = idx >> 6;
    transpose64(T2src, T2dst, H_DIM, O_DIM, e2, nb * 64 + l, kb * 512 + w * 64);
    return;
  }

  __shared__ __align__(16) unsigned short As[2][TBM * TBK];   // 2 x 16 KB
  __shared__ __align__(16) unsigned short Bs[2][TBN * TBK];   // 2 x 16 KB
  __shared__ int s_task;

  const int xcd = blockIdx.x & 7;

  // staging: slot s = i2*512 + t ; row r = s>>2 = i2*128 + (t>>2), chunk
  // c = t&3 ; LDS elem = s*8 (linear).  Global chunk gc = c ^ ((r>>1)&3)
  // = (t&3) ^ ((t>>3)&3)   (issue-invariant: 128 ≡ 0 mod 4 after >>1).
  const int gc = (t & 3) ^ ((t >> 3) & 3);
  const int sr = t >> 2;                    // 0..127

  const int wr = w >> 2, wc = w & 3;
  const int lr = l & 15, gA = l >> 4;       // gA in 0..3 (chunk index)

  for (int v = 0; v < 8; ++v) {             // home queue, then steal
    const int q = (xcd + v) & 7;
    const int nt = ntasks[q];
    const int* __restrict__ tl = tasks + q * QSTRIDE;
    for (;;) {
      if (t == 0) s_task = atomicAdd(&xctr[q], 1);
      __syncthreads();                      // publish + prev-task drain
      const int task = s_task;
      if (task >= nt) break;

      const int tk = tl[task];
      const int e  = tk >> 16;
      const int m0 = ((tk >> 8) & 255) * TBM;
      const int n0 = (tk & 255) * TBN;
      const int cnt = counts[e];
      const int* __restrict__ plist = pair_v + e * B_TOK;

      const unsigned short* aG[2];
      const unsigned short* bG[2];
      #pragma unroll
      for (int i2 = 0; i2 < 2; ++i2) {
        const int r = i2 * 128 + sr;
        const int pr = (m0 + r < cnt) ? plist[m0 + r] : -1;
        const size_t tok = (size_t)(pr < 0 ? 0 : (APAIR ? pr : (pr >> 2)));
        aG[i2] = A + tok * KDIM + gc * 8;
        bG[i2] = Bt + ((size_t)e * NDIM + n0 + r) * KDIM + gc * 8;
      }

#define STAGE(bufi, kt) do {                                   \
    const int ko_ = (kt) * TBK;                                \
    async_load16(aG[0] + ko_, &As[bufi][w * 512]);             \
    async_load16(aG[1] + ko_, &As[bufi][4096 + w * 512]);      \
    async_load16(bG[0] + ko_, &Bs[bufi][w * 512]);             \
    async_load16(bG[1] + ko_, &Bs[bufi][4096 + w * 512]);      \
  } while (0)

      f32x4 acc[8][4];
      #pragma unroll
      for (int i = 0; i < 8; ++i)
        #pragma unroll
        for (int j = 0; j < 4; ++j)
          acc[i][j] = (f32x4){0.f, 0.f, 0.f, 0.f};

      STAGE(0, 0);
      __syncthreads();                      // drains vmcnt(0): buf0 ready

      int buf = 0;
      constexpr int KIT = KDIM / TBK;       // 32 or 64
      for (int kt = 0; kt < KIT; ++kt) {
        if (kt + 1 < KIT) STAGE(buf ^ 1, kt + 1);
        bf16x8 a[8], bv[4];
        #pragma unroll
        for (int i = 0; i < 8; ++i) {
          const int ra = wr * 128 + i * 16 + lr;
          a[i] = *(const bf16x8*)&As[buf][ra * 32 + ((gA ^ ((ra >> 1) & 3)) << 3)];
        }
        #pragma unroll
        for (int j = 0; j < 4; ++j) {
          const int rb = wc * 64 + j * 16 + lr;
          bv[j] = *(const bf16x8*)&Bs[buf][rb * 32 + ((gA ^ ((rb >> 1) & 3)) << 3)];
        }
        #pragma unroll
        for (int i = 0; i < 8; ++i)
          #pragma unroll
          for (int j = 0; j < 4; ++j)
            acc[i][j] = __builtin_amdgcn_mfma_f32_16x16x32_bf16(a[i], bv[j], acc[i][j], 0, 0, 0);
        __syncthreads();                    // waits vmcnt(0): next buf landed
        buf ^= 1;
      }
#undef STAGE

      const float* __restrict__ bias = biasE + (size_t)e * NDIM + n0;
      #pragma unroll
      for (int i = 0; i < 8; ++i) {
        #pragma unroll
        for (int q2 = 0; q2 < 4; ++q2) {
          const int rl = wr * 128 + i * 16 + gA * 4 + q2;
          if (m0 + rl < cnt) {
            const int pr = plist[m0 + rl];
            #pragma unroll
            for (int j = 0; j < 4; ++j) {
              const int col = wc * 64 + j * 16 + lr;
              float vv = acc[i][j][q2] + bias[col];
              if (RELU) vv = vv > 0.f ? vv : 0.f;
              Out[(size_t)pr * NDIM + n0 + col] = f2b(vv);
            }
          }
        }
      }
    }
  }
}

// ------------------------------------------------------- softmax+y (body) ---
__device__ __forceinline__ void softmax_body(
    int b, const unsigned short* __restrict__ outw,
    const float* __restrict__ gate_bk, float* __restrict__ y)
{
  const int t = threadIdx.x;
  const int w = t >> 6, l = t & 63;
  __shared__ float acc_s[4][O_DIM];

  const unsigned short* __restrict__ row = outw + (size_t)(b * K_TOP + w) * O_DIM;
  float v[16];
  const bf16x8 r0 = *(const bf16x8*)&row[l * 16];
  const bf16x8 r1 = *(const bf16x8*)&row[l * 16 + 8];
  #pragma unroll
  for (int i = 0; i < 8; ++i) {
    v[i]     = b2f((unsigned short)r0[i]);
    v[i + 8] = b2f((unsigned short)r1[i]);
  }
  float mx = v[0];
  #pragma unroll
  for (int i = 1; i < 16; ++i) mx = fmaxf(mx, v[i]);
  #pragma unroll
  for (int off = 32; off >= 1; off >>= 1) mx = fmaxf(mx, __shfl_xor(mx, off, 64));
  float ex[16], ps = 0.f;
  #pragma unroll
  for (int i = 0; i < 16; ++i) { ex[i] = expf(v[i] - mx); ps += ex[i]; }
  #pragma unroll
  for (int off = 32; off >= 1; off >>= 1) ps += __shfl_xor(ps, off, 64);
  const float g = gate_bk[b * K_TOP + w];
  const float inv = 1.f / ps;
  #pragma unroll
  for (int i = 0; i < 16; ++i) acc_s[w][l * 16 + i] = g * expf(ex[i] * inv);
  __syncthreads();
  #pragma unroll
  for (int i = 0; i < 4; ++i) {
    const int col = t + i * 256;
    y[(size_t)b * O_DIM + col] =
        acc_s[0][col] + acc_s[1][col] + acc_s[2][col] + acc_s[3][col];
  }
}

// ------------------------------------------------------- loss part (body) ---
__device__ __forceinline__ void losspart_body(
    int blk, const float* __restrict__ gates_full,
    const float* __restrict__ prob_ws, float* __restrict__ part)
{
  const int t = threadIdx.x;
  const int e = t & 15, seg = t >> 4;
  float si = 0.f, sl = 0.f;
  #pragma unroll
  for (int j = 0; j < 4; ++j) {
    const int b = blk * 64 + seg * 4 + j;
    si += gates_full[(size_t)b * E_NUM + e];
    sl += prob_ws[(size_t)b * E_NUM + e];
  }
  __shared__ float li[16][16], ll[16][16];
  li[seg][e] = si; ll[seg][e] = sl;
  __syncthreads();
  if (t < 32) {
    const int which = t >> 4, ee = t & 15;
    float s = 0.f;
    #pragma unroll
    for (int i = 0; i < 16; ++i) s += which ? ll[i][ee] : li[i][ee];
    part[(blk * 2 + which) * 16 + ee] = s;
  }
}

// --------------------------------------------------------------- mega K4 ----
__global__ __launch_bounds__(256) void mega2_kernel(
    const unsigned short* __restrict__ outw, const float* __restrict__ gate_bk,
    float* __restrict__ y, const float* __restrict__ gates_full,
    const float* __restrict__ prob_ws, float* __restrict__ part)
{
  const int bid = blockIdx.x;
  if (bid < B_TOK) softmax_body(bid, outw, gate_bk, y);
  else             losspart_body(bid - B_TOK, gates_full, prob_ws, part);
}

__global__ __launch_bounds__(64) void loss_final_kernel(
    const float* __restrict__ part, float* __restrict__ out_loss)
{
  const int t = threadIdx.x;
  __shared__ float fi[16], fl[16];
  if (t < 32) {
    const int which = t >> 4, e = t & 15;
    float s = 0.f;
    for (int i = 0; i < 64; ++i) s += part[(i * 2 + which) * 16 + e];
    if (which) fl[e] = s; else fi[e] = s;
  }
  __syncthreads();
  if (t == 0) {
    float mi = 0.f, ml = 0.f;
    #pragma unroll
    for (int e = 0; e < 16; ++e) { mi += fi[e]; ml += fl[e]; }
    mi *= (1.f / 16.f); ml *= (1.f / 16.f);
    float vi = 0.f, vl = 0.f;
    #pragma unroll
    for (int e = 0; e < 16; ++e) {
      const float di = fi[e] - mi, dl = fl[e] - ml;
      vi += di * di; vl += dl * dl;
    }
    vi *= (1.f / 15.f); vl *= (1.f / 15.f);
    out_loss[0] = (vi / (mi * mi + 1e-10f) + vl / (ml * ml + 1e-10f)) * 0.01f;
  }
}

// ---------------------------------------------------------------- launch ----
extern "C" void kernel_launch(void* const* d_in, const int* in_sizes, int n_in,
                              void* d_out, int out_size, void* d_ws, size_t ws_size,
                              hipStream_t stream)
{
  (void)in_sizes; (void)n_in; (void)out_size;
  const float* x       = (const float*)d_in[0];
  const float* noise   = (const float*)d_in[1];
  const float* w_gate  = (const float*)d_in[2];
  const float* w_noise = (const float*)d_in[3];
  const float* W1      = (const float*)d_in[4];
  const float* b1      = (const float*)d_in[5];
  const float* W2      = (const float*)d_in[6];
  const float* b2      = (const float*)d_in[7];
  float* out = (float*)d_out;

  char* wsc = (char*)d_ws;
  int*   counts     = (int*)wsc;                          // 16
  int*   xctr       = counts + 16;                        // 16 (8 per gemm)
  int*   meta       = xctr + 16;                          // 16 (n1[8], n2[8])
  int*   tasks1     = meta + 16;                          // 8*256
  int*   tasks2     = tasks1 + 8 * 256;                   // 8*128
  int*   pair_v     = tasks2 + 8 * 128;                   // E*B
  float* gate_bk    = (float*)(pair_v + E_NUM * B_TOK);   // B*K
  float* gates_full = gate_bk + B_TOK * K_TOP;            // B*E
  float* prob_ws    = gates_full + B_TOK * E_NUM;         // B*E
  float* part       = prob_ws + B_TOK * E_NUM;            // 64*2*16
  char* big = wsc + ((((char*)(part + 64 * 2 * 16) - wsc) + 255) & ~255);
  unsigned short* x_bf = (unsigned short*)big;                         // 8.4 MB
  unsigned short* Wt1  = x_bf + (size_t)B_TOK * D_DIM;                 // 67 MB
  unsigned short* h    = Wt1 + (size_t)E_NUM * D_DIM * H_DIM;          // 67 MB
  unsigned short* outw = h + (size_t)B_TOK * K_TOP * H_DIM;            // 34 MB
  unsigned short* wt2_sep = outw + (size_t)B_TOK * K_TOP * O_DIM;      // 67 MB (opt)

  const size_t need_big =
      (size_t)((char*)(wt2_sep + (size_t)E_NUM * H_DIM * O_DIM) - wsc);
  const int bigws = (ws_size >= need_big) ? 1 : 0;
  unsigned short* Wt2 = bigws ? wt2_sep : Wt1;

  hipMemsetAsync(counts, 0, 48 * sizeof(int), stream);    // counts + xctr + meta

  // K1: gating+convert | T1 (128B-per-lane write transpose, MLP=64)
  mega1_kernel<<<B_TOK + 2048, 256, 0, stream>>>(
      x, noise, w_gate, w_noise, counts, pair_v, gate_bk, gates_full, prob_ws,
      x_bf, W1, Wt1);

  prep_tasks_kernel<<<1, 64, 0, stream>>>(counts, tasks1, tasks2, meta);

  // gemm1 (512 blocks = 2/CU) + T2 hidden underneath if bigws
  gemm256ws_kernel<H_DIM, D_DIM, true, false, 256>
      <<<512 + (bigws ? 1024 : 0), 512, 0, stream>>>(
      x_bf, Wt1, b1, counts, pair_v, tasks1, meta, xctr, h, W2, Wt2, 512);

  if (!bigws) {   // fallback: transpose W2 into Wt1 between the gemms
    transpose_dir_kernel<<<dim3(O_DIM / 64, H_DIM / 256, E_NUM), 256, 0, stream>>>(
        W2, Wt1, H_DIM, O_DIM);
  }

  gemm256ws_kernel<O_DIM, H_DIM, false, true, 128><<<512, 512, 0, stream>>>(
      h, Wt2, b2, counts, pair_v, tasks2, meta + 8, xctr + 8, outw,
      (const float*)nullptr, (unsigned short*)nullptr, 512);

  // K4: softmax_y | loss partials
  mega2_kernel<<<B_TOK + 64, 256, 0, stream>>>(outw, gate_bk, out,
                                               gates_full, prob_ws, part);
  loss_final_kernel<<<1, 64, 0, stream>>>(part, out + (size_t)B_TOK * O_DIM);
}

// Round 16
// 408.677 us; speedup vs baseline: 1.2651x; 1.2487x over previous
//
#include <hip/hip_runtime.h>
#include <math.h>

#define B_TOK 4096
#define D_DIM 1024
#define H_DIM 2048
#define O_DIM 1024
#define E_NUM 16
#define K_TOP 4

#define TBM 256
#define TBN 256
#define TBK 64   // fp8 elements (= bytes) per K-tile

typedef __attribute__((ext_vector_type(4))) float f32x4;
typedef __attribute__((ext_vector_type(8))) short bf16x8;
typedef __attribute__((ext_vector_type(4))) unsigned short u16x4;
typedef __attribute__((ext_vector_type(4))) int i32x4;

__device__ __forceinline__ unsigned short f2b(float f) {
  unsigned u = __builtin_bit_cast(unsigned, f);
  u = u + 0x7FFFu + ((u >> 16) & 1u);
  return (unsigned short)(u >> 16);
}
__device__ __forceinline__ float b2f(unsigned short s) {
  return __builtin_bit_cast(float, ((unsigned)s) << 16);
}
// pack 4 f32 -> 4 fp8(e4m3, OCP on gfx950) in one int
__device__ __forceinline__ int pk4_fp8(float a, float b, float c, float d) {
  int r = __builtin_amdgcn_cvt_pk_fp8_f32(a, b, 0, false);
  r = __builtin_amdgcn_cvt_pk_fp8_f32(c, d, r, true);
  return r;
}
__device__ __forceinline__ unsigned char f2f8(float a) {
  return (unsigned char)(__builtin_amdgcn_cvt_pk_fp8_f32(a, 0.f, 0, false) & 0xff);
}
__device__ __forceinline__ void async_load16(const void* g, void* l) {
  __builtin_amdgcn_global_load_lds(
      (const __attribute__((address_space(1))) unsigned int*)g,
      (__attribute__((address_space(3))) unsigned int*)l, 16, 0, 0);
}

// ------------------------------------------- gating + x->fp8 (body) ---------
__device__ __forceinline__ void gating_body(
    int b, const float* __restrict__ x, const float* __restrict__ noise,
    const float* __restrict__ w_gate, const float* __restrict__ w_noise,
    int* __restrict__ counts, int* __restrict__ pair_v,
    float* __restrict__ gate_bk, float* __restrict__ gates_full,
    float* __restrict__ prob_ws, unsigned char* __restrict__ xb8)
{
  const int t = threadIdx.x;
  const int e = t & 15, seg = t >> 4;           // 16 segs x 64 d each
  const float* __restrict__ xr = x + (size_t)b * D_DIM;

  float pg = 0.f, pn = 0.f;
  #pragma unroll 8
  for (int j = 0; j < 64; ++j) {
    const int d = seg * 64 + j;
    const float xv = xr[d];
    pg += xv * w_gate[d * E_NUM + e];
    pn += xv * w_noise[d * E_NUM + e];
  }
  // fused x -> fp8 (row is L1/L2-hot): thread t covers elems 4t..4t+3
  {
    const f32x4 xv4 = *(const f32x4*)&xr[t * 4];
    *(int*)&xb8[(size_t)b * D_DIM + t * 4] = pk4_fp8(xv4[0], xv4[1], xv4[2], xv4[3]);
  }
  __shared__ float sg[16][16], sn[16][16];
  sg[seg][e] = pg; sn[seg][e] = pn;
  __syncthreads();

  __shared__ float s_clean[16], s_std[16], s_noisy[16];
  if (t < 32) {
    const int which = t >> 4, ee = t & 15;
    float s = 0.f;
    #pragma unroll
    for (int i = 0; i < 16; ++i) s += which ? sn[i][ee] : sg[i][ee];
    if (which == 0) s_clean[ee] = s;
    else {
      const float sp = (s > 0.f) ? (s + log1pf(expf(-s))) : log1pf(expf(s));
      s_std[ee] = sp + 0.01f;
    }
  }
  __syncthreads();
  if (t < 16) s_noisy[t] = s_clean[t] + noise[(size_t)b * E_NUM + t] * s_std[t];
  __syncthreads();

  __shared__ float s_top[5];
  __shared__ int   s_idx[4];
  __shared__ float s_gates[4];
  if (t == 0) {
    float v[16];
    #pragma unroll
    for (int i = 0; i < 16; ++i) v[i] = s_noisy[i];
    unsigned mask = 0;
    float tv[5]; int ti[5];
    #pragma unroll
    for (int k = 0; k < 5; ++k) {
      float best = -3.4e38f; int bi = 0;
      #pragma unroll
      for (int i = 0; i < 16; ++i) {
        const bool ok = !((mask >> i) & 1u) && (v[i] > best);
        best = ok ? v[i] : best;
        bi   = ok ? i    : bi;
      }
      mask |= (1u << bi);
      tv[k] = best; ti[k] = bi;
    }
    const float m = tv[0];
    float ex[4], se = 0.f;
    #pragma unroll
    for (int k = 0; k < 4; ++k) { ex[k] = expf(tv[k] - m); se += ex[k]; }
    #pragma unroll
    for (int k = 0; k < 4; ++k) s_gates[k] = ex[k] / se;
    #pragma unroll
    for (int k = 0; k < 5; ++k) s_top[k] = tv[k];
    #pragma unroll
    for (int k = 0; k < 4; ++k) s_idx[k] = ti[k];
  }
  __syncthreads();

  if (t < 16) gates_full[(size_t)b * E_NUM + t] = 0.f;
  __syncthreads();
  if (t < 4) {
    const int ee = s_idx[t];
    const float g = s_gates[t];
    gate_bk[b * K_TOP + t] = g;
    gates_full[(size_t)b * E_NUM + ee] = g;
    const int slot = atomicAdd(&counts[ee], 1);
    pair_v[ee * B_TOK + slot] = b * K_TOP + t;     // h-row index = b*4 + rank
  }
  if (t < 16) {
    const float thr_in = s_top[4], thr_out = s_top[3];
    const float thr = (s_noisy[t] > thr_in) ? thr_in : thr_out;
    const float z = (s_clean[t] - thr) / s_std[t];
    prob_ws[(size_t)b * E_NUM + t] = 0.5f * (1.f + erff(z * 0.70710678118654752f));
  }
}

// --------------- direct transpose fp32 -> fp8, 64B-per-lane writes ----------
// in[e][R][C] fp32 -> out[e][C][R] fp8. Lane owns output row n, 64 consecutive
// k: 64 strided loads (coalesced across lanes), all issued first (MLP=64),
// then 16 pk4 converts + 4 x 16B stores = 64B contiguous per lane.
__device__ __forceinline__ void transpose64_f8(
    const float* __restrict__ in, unsigned char* __restrict__ out,
    int R, int C, int e, int n, int k0)
{
  const float* __restrict__ ip = in + (size_t)e * R * C + (size_t)k0 * C + n;
  unsigned char* __restrict__ op = out + (size_t)e * R * C + (size_t)n * R + k0;
  float v[64];
  #pragma unroll
  for (int q = 0; q < 64; ++q) v[q] = ip[(size_t)q * C];
  __builtin_amdgcn_sched_barrier(0);        // issue all 64 loads first
  #pragma unroll
  for (int g4 = 0; g4 < 4; ++g4) {
    i32x4 o;
    #pragma unroll
    for (int q = 0; q < 4; ++q) {
      const int s = g4 * 16 + q * 4;
      o[q] = pk4_fp8(v[s], v[s + 1], v[s + 2], v[s + 3]);
    }
    *(i32x4*)&op[g4 * 16] = o;
  }
}

// --------------------------------------------------------------- mega K1 ----
// gating+convert (4096) | T1: W1->Wt1 (2048 blocks, 64n x 256k tiles)
__global__ __launch_bounds__(256) void mega1_kernel(
    const float* __restrict__ x, const float* __restrict__ noise,
    const float* __restrict__ w_gate, const float* __restrict__ w_noise,
    int* __restrict__ counts, int* __restrict__ pair_v,
    float* __restrict__ gate_bk, float* __restrict__ gates_full,
    float* __restrict__ prob_ws, unsigned char* __restrict__ xb8,
    const float* __restrict__ W1, unsigned char* __restrict__ Wt1)
{
  int bid = blockIdx.x;
  if (bid < B_TOK) {
    gating_body(bid, x, noise, w_gate, w_noise, counts, pair_v,
                gate_bk, gates_full, prob_ws, xb8);
    return;
  }
  bid -= B_TOK;      // T1: R=D(k)=1024, C=H(n)=2048: nb 32 x kb 4 x e 16
  const int nb = bid & 31, kb = (bid >> 5) & 3, e = bid >> 7;
  const int w = threadIdx.x >> 6, lane = threadIdx.x & 63;
  transpose64_f8(W1, Wt1, D_DIM, H_DIM, e, nb * 64 + lane, kb * 256 + w * 64);
}

// standalone T2 (fallback path, between gemms): grid (16 nb, 8 kb, 16 e)
__global__ __launch_bounds__(256) void transpose_dir_kernel(
    const float* __restrict__ in, unsigned char* __restrict__ out,
    int R, int C)
{
  const int w = threadIdx.x >> 6, lane = threadIdx.x & 63;
  transpose64_f8(in, out, R, C, blockIdx.z, blockIdx.x * 64 + lane,
                 blockIdx.y * 256 + w * 64);
}

// -------------------------------------------------------------- prep tasks --
// Per-XCD queues; experts {x, x+8} -> XCD x.  Order (e, nb, m).
__global__ void prep_tasks_kernel(const int* __restrict__ counts,
                                  int* __restrict__ tasks1,   // [8][256]
                                  int* __restrict__ tasks2,   // [8][128]
                                  int* __restrict__ meta)     // n1[8], n2[8]
{
  const int xx = threadIdx.x;
  if (xx < 8) {
    int k1 = 0, k2 = 0;
    for (int hh = 0; hh < 2; ++hh) {
      const int e = xx + hh * 8;
      const int mb = (counts[e] + TBM - 1) / TBM;
      for (int nb = 0; nb < H_DIM / TBN; ++nb)
        for (int m = 0; m < mb; ++m)
          tasks1[xx * 256 + (k1++)] = (e << 16) | (m << 8) | nb;
      for (int nb = 0; nb < O_DIM / TBN; ++nb)
        for (int m = 0; m < mb; ++m)
          tasks2[xx * 128 + (k2++)] = (e << 16) | (m << 8) | nb;
    }
    meta[xx] = k1;
    meta[8 + xx] = k2;
  }
}

// ---- GEMM 256x256 fp8 (mfma 16x16x32_fp8_fp8), TBK=64B, 2 blocks/CU --------
// 512 thr = 8 waves (2 wr x 4 wc), 128x64 out/wave.  LDS per operand
// [2 buf][256 rows][64 B] = 32KB; 64KB total -> 2 blocks/CU.
// Staging: slot s = i2*512 + t ; row r = i2*128 + (t>>2), chunk c = t&3 (16B);
// LDS byte = s*16 (linear). Global chunk gc = c ^ ((r>>1)&3)
// = (t&3)^((t>>3)&3) (issue-invariant; R15-verified involution, 0 conflicts).
// Read (b64): lane l wants bytes [ks*32 + gA*8, +8) of its row; 16B-chunk
// cI = ks*2 + (gA>>1), swizzled cI^((row>>1)&3), +8*(gA&1).  2 lanes/bank.
template<int NDIM, int KDIM, bool RELU, bool APAIR, bool OUT8, int QSTRIDE>
__global__ __launch_bounds__(512, 1) void gemm256f8_kernel(
    const unsigned char* __restrict__ A,
    const unsigned char* __restrict__ Bt,
    const float* __restrict__ biasE,
    const int* __restrict__ counts, const int* __restrict__ pair_v,
    const int* __restrict__ tasks,     // [8][QSTRIDE]
    const int* __restrict__ ntasks,    // [8]
    int* __restrict__ xctr,            // [8]
    unsigned char* __restrict__ Out8, unsigned short* __restrict__ Out16,
    const float* __restrict__ T2src, unsigned char* __restrict__ T2dst,
    int ngemm)
{
  const int t = threadIdx.x;
  const int w = t >> 6, l = t & 63;

  if ((int)blockIdx.x >= ngemm) {   // T2: R=H(k)=2048, C=O(n)=1024
    const int idx = (int)blockIdx.x - ngemm;   // nb 16 x kb 4 x e 16
    const int nb = idx & 15, kb = (idx >> 4) & 3, e2 = idx >> 6;
    transpose64_f8(T2src, T2dst, H_DIM, O_DIM, e2, nb * 64 + l,
                   kb * 512 + w * 64);
    return;
  }

  __shared__ __align__(16) unsigned char As[2][TBM * TBK];   // 2 x 16 KB
  __shared__ __align__(16) unsigned char Bs[2][TBN * TBK];   // 2 x 16 KB
  __shared__ int s_task;

  const int xcd = blockIdx.x & 7;

  const int gc = (t & 3) ^ ((t >> 3) & 3);   // issue-invariant global chunk
  const int sr = t >> 2;                     // staging row 0..127

  const int wr = w >> 2, wc = w & 3;
  const int lr = l & 15, gA = l >> 4;        // gA in 0..3

  for (int v = 0; v < 8; ++v) {              // home queue, then steal
    const int q = (xcd + v) & 7;
    const int nt = ntasks[q];
    const int* __restrict__ tl = tasks + q * QSTRIDE;
    for (;;) {
      if (t == 0) s_task = atomicAdd(&xctr[q], 1);
      __syncthreads();                       // publish + prev-task drain
      const int task = s_task;
      if (task >= nt) break;

      const int tk = tl[task];
      const int e  = tk >> 16;
      const int m0 = ((tk >> 8) & 255) * TBM;
      const int n0 = (tk & 255) * TBN;
      const int cnt = counts[e];
      const int* __restrict__ plist = pair_v + e * B_TOK;

      const unsigned char* aG[2];
      const unsigned char* bG[2];
      #pragma unroll
      for (int i2 = 0; i2 < 2; ++i2) {
        const int r = i2 * 128 + sr;
        const int pr = (m0 + r < cnt) ? plist[m0 + r] : -1;
        const size_t tok = (size_t)(pr < 0 ? 0 : (APAIR ? pr : (pr >> 2)));
        aG[i2] = A + tok * KDIM + gc * 16;
        bG[i2] = Bt + ((size_t)e * NDIM + n0 + r) * KDIM + gc * 16;
      }

#define STAGE(bufi, kt) do {                                   \
    const int ko_ = (kt) * TBK;                                \
    async_load16(aG[0] + ko_, &As[bufi][w * 1024]);            \
    async_load16(aG[1] + ko_, &As[bufi][8192 + w * 1024]);     \
    async_load16(bG[0] + ko_, &Bs[bufi][w * 1024]);            \
    async_load16(bG[1] + ko_, &Bs[bufi][8192 + w * 1024]);     \
  } while (0)

      f32x4 acc[8][4];
      #pragma unroll
      for (int i = 0; i < 8; ++i)
        #pragma unroll
        for (int j = 0; j < 4; ++j)
          acc[i][j] = (f32x4){0.f, 0.f, 0.f, 0.f};

      STAGE(0, 0);
      __syncthreads();                       // drains vmcnt(0): buf0 ready

      int buf = 0;
      constexpr int KIT = KDIM / TBK;        // 16 or 32
      for (int kt = 0; kt < KIT; ++kt) {
        if (kt + 1 < KIT) STAGE(buf ^ 1, kt + 1);
        #pragma unroll
        for (int ks = 0; ks < 2; ++ks) {
          long a8[8]; long b8[4];
          #pragma unroll
          for (int i = 0; i < 8; ++i) {
            const int ra = wr * 128 + i * 16 + lr;
            const int cI = (ks * 2 + (gA >> 1)) ^ ((ra >> 1) & 3);
            a8[i] = *(const long*)&As[buf][ra * 64 + cI * 16 + (gA & 1) * 8];
          }
          #pragma unroll
          for (int j = 0; j < 4; ++j) {
            const int rb = wc * 64 + j * 16 + lr;
            const int cI = (ks * 2 + (gA >> 1)) ^ ((rb >> 1) & 3);
            b8[j] = *(const long*)&Bs[buf][rb * 64 + cI * 16 + (gA & 1) * 8];
          }
          #pragma unroll
          for (int i = 0; i < 8; ++i)
            #pragma unroll
            for (int j = 0; j < 4; ++j)
              acc[i][j] = __builtin_amdgcn_mfma_f32_16x16x32_fp8_fp8(
                  a8[i], b8[j], acc[i][j], 0, 0, 0);
        }
        __syncthreads();                     // waits vmcnt(0): next buf landed
        buf ^= 1;
      }
#undef STAGE

      const float* __restrict__ bias = biasE + (size_t)e * NDIM + n0;
      #pragma unroll
      for (int i = 0; i < 8; ++i) {
        #pragma unroll
        for (int q2 = 0; q2 < 4; ++q2) {
          const int rl = wr * 128 + i * 16 + gA * 4 + q2;
          if (m0 + rl < cnt) {
            const int pr = plist[m0 + rl];
            #pragma unroll
            for (int j = 0; j < 4; ++j) {
              const int col = wc * 64 + j * 16 + lr;
              float vv = acc[i][j][q2] + bias[col];
              if (RELU) vv = vv > 0.f ? vv : 0.f;
              if (OUT8) Out8[(size_t)pr * NDIM + n0 + col] = f2f8(vv);
              else      Out16[(size_t)pr * NDIM + n0 + col] = f2b(vv);
            }
          }
        }
      }
    }
  }
}

// ------------------------------------------------------- softmax+y (body) ---
__device__ __forceinline__ void softmax_body(
    int b, const unsigned short* __restrict__ outw,
    const float* __restrict__ gate_bk, float* __restrict__ y)
{
  const int t = threadIdx.x;
  const int w = t >> 6, l = t & 63;
  __shared__ float acc_s[4][O_DIM];

  const unsigned short* __restrict__ row = outw + (size_t)(b * K_TOP + w) * O_DIM;
  float v[16];
  const bf16x8 r0 = *(const bf16x8*)&row[l * 16];
  const bf16x8 r1 = *(const bf16x8*)&row[l * 16 + 8];
  #pragma unroll
  for (int i = 0; i < 8; ++i) {
    v[i]     = b2f((unsigned short)r0[i]);
    v[i + 8] = b2f((unsigned short)r1[i]);
  }
  float mx = v[0];
  #pragma unroll
  for (int i = 1; i < 16; ++i) mx = fmaxf(mx, v[i]);
  #pragma unroll
  for (int off = 32; off >= 1; off >>= 1) mx = fmaxf(mx, __shfl_xor(mx, off, 64));
  float ex[16], ps = 0.f;
  #pragma unroll
  for (int i = 0; i < 16; ++i) { ex[i] = expf(v[i] - mx); ps += ex[i]; }
  #pragma unroll
  for (int off = 32; off >= 1; off >>= 1) ps += __shfl_xor(ps, off, 64);
  const float g = gate_bk[b * K_TOP + w];
  const float inv = 1.f / ps;
  #pragma unroll
  for (int i = 0; i < 16; ++i) acc_s[w][l * 16 + i] = g * expf(ex[i] * inv);
  __syncthreads();
  #pragma unroll
  for (int i = 0; i < 4; ++i) {
    const int col = t + i * 256;
    y[(size_t)b * O_DIM + col] =
        acc_s[0][col] + acc_s[1][col] + acc_s[2][col] + acc_s[3][col];
  }
}

// ------------------------------------------------------- loss part (body) ---
__device__ __forceinline__ void losspart_body(
    int blk, const float* __restrict__ gates_full,
    const float* __restrict__ prob_ws, float* __restrict__ part)
{
  const int t = threadIdx.x;
  const int e = t & 15, seg = t >> 4;
  float si = 0.f, sl = 0.f;
  #pragma unroll
  for (int j = 0; j < 4; ++j) {
    const int b = blk * 64 + seg * 4 + j;
    si += gates_full[(size_t)b * E_NUM + e];
    sl += prob_ws[(size_t)b * E_NUM + e];
  }
  __shared__ float li[16][16], ll[16][16];
  li[seg][e] = si; ll[seg][e] = sl;
  __syncthreads();
  if (t < 32) {
    const int which = t >> 4, ee = t & 15;
    float s = 0.f;
    #pragma unroll
    for (int i = 0; i < 16; ++i) s += which ? ll[i][ee] : li[i][ee];
    part[(blk * 2 + which) * 16 + ee] = s;
  }
}

// --------------------------------------------------------------- mega K4 ----
__global__ __launch_bounds__(256) void mega2_kernel(
    const unsigned short* __restrict__ outw, const float* __restrict__ gate_bk,
    float* __restrict__ y, const float* __restrict__ gates_full,
    const float* __restrict__ prob_ws, float* __restrict__ part)
{
  const int bid = blockIdx.x;
  if (bid < B_TOK) softmax_body(bid, outw, gate_bk, y);
  else             losspart_body(bid - B_TOK, gates_full, prob_ws, part);
}

__global__ __launch_bounds__(64) void loss_final_kernel(
    const float* __restrict__ part, float* __restrict__ out_loss)
{
  const int t = threadIdx.x;
  __shared__ float fi[16], fl[16];
  if (t < 32) {
    const int which = t >> 4, e = t & 15;
    float s = 0.f;
    for (int i = 0; i < 64; ++i) s += part[(i * 2 + which) * 16 + e];
    if (which) fl[e] = s; else fi[e] = s;
  }
  __syncthreads();
  if (t == 0) {
    float mi = 0.f, ml = 0.f;
    #pragma unroll
    for (int e = 0; e < 16; ++e) { mi += fi[e]; ml += fl[e]; }
    mi *= (1.f / 16.f); ml *= (1.f / 16.f);
    float vi = 0.f, vl = 0.f;
    #pragma unroll
    for (int e = 0; e < 16; ++e) {
      const float di = fi[e] - mi, dl = fl[e] - ml;
      vi += di * di; vl += dl * dl;
    }
    vi *= (1.f / 15.f); vl *= (1.f / 15.f);
    out_loss[0] = (vi / (mi * mi + 1e-10f) + vl / (ml * ml + 1e-10f)) * 0.01f;
  }
}

// ---------------------------------------------------------------- launch ----
extern "C" void kernel_launch(void* const* d_in, const int* in_sizes, int n_in,
                              void* d_out, int out_size, void* d_ws, size_t ws_size,
                              hipStream_t stream)
{
  (void)in_sizes; (void)n_in; (void)out_size;
  const float* x       = (const float*)d_in[0];
  const float* noise   = (const float*)d_in[1];
  const float* w_gate  = (const float*)d_in[2];
  const float* w_noise = (const float*)d_in[3];
  const float* W1      = (const float*)d_in[4];
  const float* b1      = (const float*)d_in[5];
  const float* W2      = (const float*)d_in[6];
  const float* b2      = (const float*)d_in[7];
  float* out = (float*)d_out;

  char* wsc = (char*)d_ws;
  int*   counts     = (int*)wsc;                          // 16
  int*   xctr       = counts + 16;                        // 16 (8 per gemm)
  int*   meta       = xctr + 16;                          // 16 (n1[8], n2[8])
  int*   tasks1     = meta + 16;                          // 8*256
  int*   tasks2     = tasks1 + 8 * 256;                   // 8*128
  int*   pair_v     = tasks2 + 8 * 128;                   // E*B
  float* gate_bk    = (float*)(pair_v + E_NUM * B_TOK);   // B*K
  float* gates_full = gate_bk + B_TOK * K_TOP;            // B*E
  float* prob_ws    = gates_full + B_TOK * E_NUM;         // B*E
  float* part       = prob_ws + B_TOK * E_NUM;            // 64*2*16
  char* big = wsc + ((((char*)(part + 64 * 2 * 16) - wsc) + 255) & ~255);
  unsigned char* x8   = (unsigned char*)big;                          // 4.2 MB
  unsigned char* Wt1  = x8 + (size_t)B_TOK * D_DIM;                   // 33.5 MB
  unsigned char* h8   = Wt1 + (size_t)E_NUM * D_DIM * H_DIM;          // 33.5 MB
  unsigned short* outw = (unsigned short*)(h8 + (size_t)B_TOK * K_TOP * H_DIM); // 33.5 MB
  unsigned char* wt2_sep = (unsigned char*)(outw + (size_t)B_TOK * K_TOP * O_DIM); // 33.5 MB

  const size_t need_big =
      (size_t)((char*)(wt2_sep + (size_t)E_NUM * H_DIM * O_DIM) - wsc);
  const int bigws = (ws_size >= need_big) ? 1 : 0;
  unsigned char* Wt2 = bigws ? wt2_sep : Wt1;

  hipMemsetAsync(counts, 0, 48 * sizeof(int), stream);    // counts + xctr + meta

  // K1: gating+convert | T1 (fp8 transpose, MLP=64)
  mega1_kernel<<<B_TOK + 2048, 256, 0, stream>>>(
      x, noise, w_gate, w_noise, counts, pair_v, gate_bk, gates_full, prob_ws,
      x8, W1, Wt1);

  prep_tasks_kernel<<<1, 64, 0, stream>>>(counts, tasks1, tasks2, meta);

  // gemm1 (512 blocks = 2/CU) + T2 hidden underneath if bigws
  gemm256f8_kernel<H_DIM, D_DIM, true, false, true, 256>
      <<<512 + (bigws ? 1024 : 0), 512, 0, stream>>>(
      x8, Wt1, b1, counts, pair_v, tasks1, meta, xctr,
      h8, (unsigned short*)nullptr, W2, Wt2, 512);

  if (!bigws) {   // fallback: transpose W2 into Wt1 between the gemms
    transpose_dir_kernel<<<dim3(O_DIM / 64, H_DIM / 256, E_NUM), 256, 0, stream>>>(
        W2, Wt1, H_DIM, O_DIM);
  }

  gemm256f8_kernel<O_DIM, H_DIM, false, true, false, 128><<<512, 512, 0, stream>>>(
      h8, Wt2, b2, counts, pair_v, tasks2, meta + 8, xctr + 8,
      (unsigned char*)nullptr, outw, (const float*)nullptr,
      (unsigned char*)nullptr, 512);

  // K4: softmax_y | loss partials
  mega2_kernel<<<B_TOK + 64, 256, 0, stream>>>(outw, gate_bk, out,
                                               gates_full, prob_ws, part);
  loss_final_kernel<<<1, 64, 0, stream>>>(part, out + (size_t)B_TOK * O_DIM);
}

// Round 17
// 361.818 us; speedup vs baseline: 1.4290x; 1.1295x over previous
//
#include <hip/hip_runtime.h>
#include <math.h>

#define B_TOK 4096
#define D_DIM 1024
#define H_DIM 2048
#define O_DIM 1024
#define E_NUM 16
#define K_TOP 4

#define TBM 256
#define TBN 256
#define TBK 128   // fp8 elements (= bytes) per K-tile

typedef __attribute__((ext_vector_type(4))) float f32x4;
typedef __attribute__((ext_vector_type(8))) short bf16x8;
typedef __attribute__((ext_vector_type(4))) unsigned short u16x4;
typedef __attribute__((ext_vector_type(4))) int i32x4;

__device__ __forceinline__ unsigned short f2b(float f) {
  unsigned u = __builtin_bit_cast(unsigned, f);
  u = u + 0x7FFFu + ((u >> 16) & 1u);
  return (unsigned short)(u >> 16);
}
__device__ __forceinline__ float b2f(unsigned short s) {
  return __builtin_bit_cast(float, ((unsigned)s) << 16);
}
// pack 4 f32 -> 4 fp8(e4m3, OCP on gfx950) in one int
__device__ __forceinline__ int pk4_fp8(float a, float b, float c, float d) {
  int r = __builtin_amdgcn_cvt_pk_fp8_f32(a, b, 0, false);
  r = __builtin_amdgcn_cvt_pk_fp8_f32(c, d, r, true);
  return r;
}
__device__ __forceinline__ unsigned char f2f8(float a) {
  return (unsigned char)(__builtin_amdgcn_cvt_pk_fp8_f32(a, 0.f, 0, false) & 0xff);
}
__device__ __forceinline__ void async_load16(const void* g, void* l) {
  __builtin_amdgcn_global_load_lds(
      (const __attribute__((address_space(1))) unsigned int*)g,
      (__attribute__((address_space(3))) unsigned int*)l, 16, 0, 0);
}

// ------------------------------------------- gating + x->fp8 (body) ---------
__device__ __forceinline__ void gating_body(
    int b, const float* __restrict__ x, const float* __restrict__ noise,
    const float* __restrict__ w_gate, const float* __restrict__ w_noise,
    int* __restrict__ counts, int* __restrict__ pair_v,
    float* __restrict__ gate_bk, float* __restrict__ gates_full,
    float* __restrict__ prob_ws, unsigned char* __restrict__ xb8)
{
  const int t = threadIdx.x;
  const int e = t & 15, seg = t >> 4;           // 16 segs x 64 d each
  const float* __restrict__ xr = x + (size_t)b * D_DIM;

  float pg = 0.f, pn = 0.f;
  #pragma unroll 8
  for (int j = 0; j < 64; ++j) {
    const int d = seg * 64 + j;
    const float xv = xr[d];
    pg += xv * w_gate[d * E_NUM + e];
    pn += xv * w_noise[d * E_NUM + e];
  }
  // fused x -> fp8 (row is L1/L2-hot): thread t covers elems 4t..4t+3
  {
    const f32x4 xv4 = *(const f32x4*)&xr[t * 4];
    *(int*)&xb8[(size_t)b * D_DIM + t * 4] = pk4_fp8(xv4[0], xv4[1], xv4[2], xv4[3]);
  }
  __shared__ float sg[16][16], sn[16][16];
  sg[seg][e] = pg; sn[seg][e] = pn;
  __syncthreads();

  __shared__ float s_clean[16], s_std[16], s_noisy[16];
  if (t < 32) {
    const int which = t >> 4, ee = t & 15;
    float s = 0.f;
    #pragma unroll
    for (int i = 0; i < 16; ++i) s += which ? sn[i][ee] : sg[i][ee];
    if (which == 0) s_clean[ee] = s;
    else {
      const float sp = (s > 0.f) ? (s + log1pf(expf(-s))) : log1pf(expf(s));
      s_std[ee] = sp + 0.01f;
    }
  }
  __syncthreads();
  if (t < 16) s_noisy[t] = s_clean[t] + noise[(size_t)b * E_NUM + t] * s_std[t];
  __syncthreads();

  __shared__ float s_top[5];
  __shared__ int   s_idx[4];
  __shared__ float s_gates[4];
  if (t == 0) {
    float v[16];
    #pragma unroll
    for (int i = 0; i < 16; ++i) v[i] = s_noisy[i];
    unsigned mask = 0;
    float tv[5]; int ti[5];
    #pragma unroll
    for (int k = 0; k < 5; ++k) {
      float best = -3.4e38f; int bi = 0;
      #pragma unroll
      for (int i = 0; i < 16; ++i) {
        const bool ok = !((mask >> i) & 1u) && (v[i] > best);
        best = ok ? v[i] : best;
        bi   = ok ? i    : bi;
      }
      mask |= (1u << bi);
      tv[k] = best; ti[k] = bi;
    }
    const float m = tv[0];
    float ex[4], se = 0.f;
    #pragma unroll
    for (int k = 0; k < 4; ++k) { ex[k] = expf(tv[k] - m); se += ex[k]; }
    #pragma unroll
    for (int k = 0; k < 4; ++k) s_gates[k] = ex[k] / se;
    #pragma unroll
    for (int k = 0; k < 5; ++k) s_top[k] = tv[k];
    #pragma unroll
    for (int k = 0; k < 4; ++k) s_idx[k] = ti[k];
  }
  __syncthreads();

  if (t < 16) gates_full[(size_t)b * E_NUM + t] = 0.f;
  __syncthreads();
  if (t < 4) {
    const int ee = s_idx[t];
    const float g = s_gates[t];
    gate_bk[b * K_TOP + t] = g;
    gates_full[(size_t)b * E_NUM + ee] = g;
    const int slot = atomicAdd(&counts[ee], 1);
    pair_v[ee * B_TOK + slot] = b * K_TOP + t;     // h-row index = b*4 + rank
  }
  if (t < 16) {
    const float thr_in = s_top[4], thr_out = s_top[3];
    const float thr = (s_noisy[t] > thr_in) ? thr_in : thr_out;
    const float z = (s_clean[t] - thr) / s_std[t];
    prob_ws[(size_t)b * E_NUM + t] = 0.5f * (1.f + erff(z * 0.70710678118654752f));
  }
}

// --------------- direct transpose fp32 -> fp8, 64B-per-lane writes ----------
__device__ __forceinline__ void transpose64_f8(
    const float* __restrict__ in, unsigned char* __restrict__ out,
    int R, int C, int e, int n, int k0)
{
  const float* __restrict__ ip = in + (size_t)e * R * C + (size_t)k0 * C + n;
  unsigned char* __restrict__ op = out + (size_t)e * R * C + (size_t)n * R + k0;
  float v[64];
  #pragma unroll
  for (int q = 0; q < 64; ++q) v[q] = ip[(size_t)q * C];
  __builtin_amdgcn_sched_barrier(0);        // issue all 64 loads first
  #pragma unroll
  for (int g4 = 0; g4 < 4; ++g4) {
    i32x4 o;
    #pragma unroll
    for (int q = 0; q < 4; ++q) {
      const int s = g4 * 16 + q * 4;
      o[q] = pk4_fp8(v[s], v[s + 1], v[s + 2], v[s + 3]);
    }
    *(i32x4*)&op[g4 * 16] = o;
  }
}

// --------------------------------------------------------------- mega K1 ----
// gating+convert (4096) | T1: W1->Wt1 (2048 blocks, 64n x 256k tiles)
__global__ __launch_bounds__(256) void mega1_kernel(
    const float* __restrict__ x, const float* __restrict__ noise,
    const float* __restrict__ w_gate, const float* __restrict__ w_noise,
    int* __restrict__ counts, int* __restrict__ pair_v,
    float* __restrict__ gate_bk, float* __restrict__ gates_full,
    float* __restrict__ prob_ws, unsigned char* __restrict__ xb8,
    const float* __restrict__ W1, unsigned char* __restrict__ Wt1)
{
  int bid = blockIdx.x;
  if (bid < B_TOK) {
    gating_body(bid, x, noise, w_gate, w_noise, counts, pair_v,
                gate_bk, gates_full, prob_ws, xb8);
    return;
  }
  bid -= B_TOK;      // T1: R=D(k)=1024, C=H(n)=2048: nb 32 x kb 4 x e 16
  const int nb = bid & 31, kb = (bid >> 5) & 3, e = bid >> 7;
  const int w = threadIdx.x >> 6, lane = threadIdx.x & 63;
  transpose64_f8(W1, Wt1, D_DIM, H_DIM, e, nb * 64 + lane, kb * 256 + w * 64);
}

// standalone T2 (fallback path, between gemms): grid (16 nb, 8 kb, 16 e)
__global__ __launch_bounds__(256) void transpose_dir_kernel(
    const float* __restrict__ in, unsigned char* __restrict__ out,
    int R, int C)
{
  const int w = threadIdx.x >> 6, lane = threadIdx.x & 63;
  transpose64_f8(in, out, R, C, blockIdx.z, blockIdx.x * 64 + lane,
                 blockIdx.y * 256 + w * 64);
}

// -------------------------------------------------------------- prep tasks --
// Per-XCD queues; experts {x, x+8} -> XCD x.  Order (e, nb, m).
__global__ void prep_tasks_kernel(const int* __restrict__ counts,
                                  int* __restrict__ tasks1,   // [8][256]
                                  int* __restrict__ tasks2,   // [8][128]
                                  int* __restrict__ meta)     // n1[8], n2[8]
{
  const int xx = threadIdx.x;
  if (xx < 8) {
    int k1 = 0, k2 = 0;
    for (int hh = 0; hh < 2; ++hh) {
      const int e = xx + hh * 8;
      const int mb = (counts[e] + TBM - 1) / TBM;
      for (int nb = 0; nb < H_DIM / TBN; ++nb)
        for (int m = 0; m < mb; ++m)
          tasks1[xx * 256 + (k1++)] = (e << 16) | (m << 8) | nb;
      for (int nb = 0; nb < O_DIM / TBN; ++nb)
        for (int m = 0; m < mb; ++m)
          tasks2[xx * 128 + (k2++)] = (e << 16) | (m << 8) | nb;
    }
    meta[xx] = k1;
    meta[8 + xx] = k2;
  }
}

// ---- GEMM 256x256 fp8, TBK=128B (KIT halved), 1 block/CU, 128KB LDS --------
// 512 thr = 8 waves (2 wr x 4 wc), 128x64 out/wave; 128 MFMA/kt/wave.
// Staging (R13-proven 8-chunk involution): slot s = i*512 + t, row r =
// i*64 + (t>>3), chunk c = t&7; LDS byte = s*16 (linear). Global chunk
// gc = c ^ (r&7) = (t&7)^((t>>3)&7)  (issue-invariant since 64%8==0).
// Read (b64): ks=0..3; 16B chunk cI = ks*2+(gA>>1), swizzled cI^(row&7),
// + 8*(gA&1).  (Structural 4-way for wave-wide b64 — acceptable.)
template<int NDIM, int KDIM, bool RELU, bool APAIR, bool OUT8, int QSTRIDE>
__global__ __launch_bounds__(512, 1) void gemm256f8_kernel(
    const unsigned char* __restrict__ A,
    const unsigned char* __restrict__ Bt,
    const float* __restrict__ biasE,
    const int* __restrict__ counts, const int* __restrict__ pair_v,
    const int* __restrict__ tasks,     // [8][QSTRIDE]
    const int* __restrict__ ntasks,    // [8]
    int* __restrict__ xctr,            // [8]
    unsigned char* __restrict__ Out8, unsigned short* __restrict__ Out16,
    const float* __restrict__ T2src, unsigned char* __restrict__ T2dst,
    int ngemm)
{
  const int t = threadIdx.x;
  const int w = t >> 6, l = t & 63;

  if ((int)blockIdx.x >= ngemm) {   // T2: R=H(k)=2048, C=O(n)=1024
    const int idx = (int)blockIdx.x - ngemm;   // nb 16 x kb 4 x e 16
    const int nb = idx & 15, kb = (idx >> 4) & 3, e2 = idx >> 6;
    transpose64_f8(T2src, T2dst, H_DIM, O_DIM, e2, nb * 64 + l,
                   kb * 512 + w * 64);
    return;
  }

  __shared__ __align__(16) unsigned char As[2][TBM * TBK];   // 2 x 32 KB
  __shared__ __align__(16) unsigned char Bs[2][TBN * TBK];   // 2 x 32 KB
  __shared__ int s_task;

  const int xcd = blockIdx.x & 7;

  const int gc = (t & 7) ^ ((t >> 3) & 7);   // issue-invariant global chunk
  const int sr = t >> 3;                     // staging row 0..63

  const int wr = w >> 2, wc = w & 3;
  const int lr = l & 15, gA = l >> 4;        // gA in 0..3

  for (int v = 0; v < 8; ++v) {              // home queue, then steal
    const int q = (xcd + v) & 7;
    const int nt = ntasks[q];
    const int* __restrict__ tl = tasks + q * QSTRIDE;
    for (;;) {
      if (t == 0) s_task = atomicAdd(&xctr[q], 1);
      __syncthreads();                       // publish + prev-task drain
      const int task = s_task;
      if (task >= nt) break;

      const int tk = tl[task];
      const int e  = tk >> 16;
      const int m0 = ((tk >> 8) & 255) * TBM;
      const int n0 = (tk & 255) * TBN;
      const int cnt = counts[e];
      const int* __restrict__ plist = pair_v + e * B_TOK;

      const unsigned char* aG[4];
      const unsigned char* bG[4];
      #pragma unroll
      for (int i = 0; i < 4; ++i) {
        const int r = i * 64 + sr;
        const int pr = (m0 + r < cnt) ? plist[m0 + r] : -1;
        const size_t tok = (size_t)(pr < 0 ? 0 : (APAIR ? pr : (pr >> 2)));
        aG[i] = A + tok * KDIM + gc * 16;
        bG[i] = Bt + ((size_t)e * NDIM + n0 + r) * KDIM + gc * 16;
      }

#define STAGE(bufi, kt) do {                                        \
    const int ko_ = (kt) * TBK;                                     \
    _Pragma("unroll")                                               \
    for (int i_ = 0; i_ < 4; ++i_) {                                \
      async_load16(aG[i_] + ko_, &As[bufi][i_ * 8192 + w * 1024]);  \
      async_load16(bG[i_] + ko_, &Bs[bufi][i_ * 8192 + w * 1024]);  \
    }                                                               \
  } while (0)

      f32x4 acc[8][4];
      #pragma unroll
      for (int i = 0; i < 8; ++i)
        #pragma unroll
        for (int j = 0; j < 4; ++j)
          acc[i][j] = (f32x4){0.f, 0.f, 0.f, 0.f};

      STAGE(0, 0);
      __syncthreads();                       // drains vmcnt(0): buf0 ready

      int buf = 0;
      constexpr int KIT = KDIM / TBK;        // 8 or 16
      for (int kt = 0; kt < KIT; ++kt) {
        if (kt + 1 < KIT) STAGE(buf ^ 1, kt + 1);
        #pragma unroll
        for (int ks = 0; ks < 4; ++ks) {
          long a8[8]; long b8[4];
          #pragma unroll
          for (int i = 0; i < 8; ++i) {
            const int ra = wr * 128 + i * 16 + lr;
            const int cI = (ks * 2 + (gA >> 1)) ^ (ra & 7);
            a8[i] = *(const long*)&As[buf][ra * 128 + cI * 16 + (gA & 1) * 8];
          }
          #pragma unroll
          for (int j = 0; j < 4; ++j) {
            const int rb = wc * 64 + j * 16 + lr;
            const int cI = (ks * 2 + (gA >> 1)) ^ (rb & 7);
            b8[j] = *(const long*)&Bs[buf][rb * 128 + cI * 16 + (gA & 1) * 8];
          }
          #pragma unroll
          for (int i = 0; i < 8; ++i)
            #pragma unroll
            for (int j = 0; j < 4; ++j)
              acc[i][j] = __builtin_amdgcn_mfma_f32_16x16x32_fp8_fp8(
                  a8[i], b8[j], acc[i][j], 0, 0, 0);
        }
        __syncthreads();                     // waits vmcnt(0): next buf landed
        buf ^= 1;
      }
#undef STAGE

      const float* __restrict__ bias = biasE + (size_t)e * NDIM + n0;
      #pragma unroll
      for (int i = 0; i < 8; ++i) {
        #pragma unroll
        for (int q2 = 0; q2 < 4; ++q2) {
          const int rl = wr * 128 + i * 16 + gA * 4 + q2;
          if (m0 + rl < cnt) {
            const int pr = plist[m0 + rl];
            #pragma unroll
            for (int j = 0; j < 4; ++j) {
              const int col = wc * 64 + j * 16 + lr;
              float vv = acc[i][j][q2] + bias[col];
              if (RELU) vv = vv > 0.f ? vv : 0.f;
              if (OUT8) Out8[(size_t)pr * NDIM + n0 + col] = f2f8(vv);
              else      Out16[(size_t)pr * NDIM + n0 + col] = f2b(vv);
            }
          }
        }
      }
    }
  }
}

// ------------------------------------------------------- softmax+y (body) ---
__device__ __forceinline__ void softmax_body(
    int b, const unsigned short* __restrict__ outw,
    const float* __restrict__ gate_bk, float* __restrict__ y)
{
  const int t = threadIdx.x;
  const int w = t >> 6, l = t & 63;
  __shared__ float acc_s[4][O_DIM];

  const unsigned short* __restrict__ row = outw + (size_t)(b * K_TOP + w) * O_DIM;
  float v[16];
  const bf16x8 r0 = *(const bf16x8*)&row[l * 16];
  const bf16x8 r1 = *(const bf16x8*)&row[l * 16 + 8];
  #pragma unroll
  for (int i = 0; i < 8; ++i) {
    v[i]     = b2f((unsigned short)r0[i]);
    v[i + 8] = b2f((unsigned short)r1[i]);
  }
  float mx = v[0];
  #pragma unroll
  for (int i = 1; i < 16; ++i) mx = fmaxf(mx, v[i]);
  #pragma unroll
  for (int off = 32; off >= 1; off >>= 1) mx = fmaxf(mx, __shfl_xor(mx, off, 64));
  float ex[16], ps = 0.f;
  #pragma unroll
  for (int i = 0; i < 16; ++i) { ex[i] = expf(v[i] - mx); ps += ex[i]; }
  #pragma unroll
  for (int off = 32; off >= 1; off >>= 1) ps += __shfl_xor(ps, off, 64);
  const float g = gate_bk[b * K_TOP + w];
  const float inv = 1.f / ps;
  #pragma unroll
  for (int i = 0; i < 16; ++i) acc_s[w][l * 16 + i] = g * expf(ex[i] * inv);
  __syncthreads();
  #pragma unroll
  for (int i = 0; i < 4; ++i) {
    const int col = t + i * 256;
    y[(size_t)b * O_DIM + col] =
        acc_s[0][col] + acc_s[1][col] + acc_s[2][col] + acc_s[3][col];
  }
}

// ------------------------------------------------------- loss part (body) ---
__device__ __forceinline__ void losspart_body(
    int blk, const float* __restrict__ gates_full,
    const float* __restrict__ prob_ws, float* __restrict__ part)
{
  const int t = threadIdx.x;
  const int e = t & 15, seg = t >> 4;
  float si = 0.f, sl = 0.f;
  #pragma unroll
  for (int j = 0; j < 4; ++j) {
    const int b = blk * 64 + seg * 4 + j;
    si += gates_full[(size_t)b * E_NUM + e];
    sl += prob_ws[(size_t)b * E_NUM + e];
  }
  __shared__ float li[16][16], ll[16][16];
  li[seg][e] = si; ll[seg][e] = sl;
  __syncthreads();
  if (t < 32) {
    const int which = t >> 4, ee = t & 15;
    float s = 0.f;
    #pragma unroll
    for (int i = 0; i < 16; ++i) s += which ? ll[i][ee] : li[i][ee];
    part[(blk * 2 + which) * 16 + ee] = s;
  }
}

// --------------------------------------------------------------- mega K4 ----
__global__ __launch_bounds__(256) void mega2_kernel(
    const unsigned short* __restrict__ outw, const float* __restrict__ gate_bk,
    float* __restrict__ y, const float* __restrict__ gates_full,
    const float* __restrict__ prob_ws, float* __restrict__ part)
{
  const int bid = blockIdx.x;
  if (bid < B_TOK) softmax_body(bid, outw, gate_bk, y);
  else             losspart_body(bid - B_TOK, gates_full, prob_ws, part);
}

__global__ __launch_bounds__(64) void loss_final_kernel(
    const float* __restrict__ part, float* __restrict__ out_loss)
{
  const int t = threadIdx.x;
  __shared__ float fi[16], fl[16];
  if (t < 32) {
    const int which = t >> 4, e = t & 15;
    float s = 0.f;
    for (int i = 0; i < 64; ++i) s += part[(i * 2 + which) * 16 + e];
    if (which) fl[e] = s; else fi[e] = s;
  }
  __syncthreads();
  if (t == 0) {
    float mi = 0.f, ml = 0.f;
    #pragma unroll
    for (int e = 0; e < 16; ++e) { mi += fi[e]; ml += fl[e]; }
    mi *= (1.f / 16.f); ml *= (1.f / 16.f);
    float vi = 0.f, vl = 0.f;
    #pragma unroll
    for (int e = 0; e < 16; ++e) {
      const float di = fi[e] - mi, dl = fl[e] - ml;
      vi += di * di; vl += dl * dl;
    }
    vi *= (1.f / 15.f); vl *= (1.f / 15.f);
    out_loss[0] = (vi / (mi * mi + 1e-10f) + vl / (ml * ml + 1e-10f)) * 0.01f;
  }
}

// ---------------------------------------------------------------- launch ----
extern "C" void kernel_launch(void* const* d_in, const int* in_sizes, int n_in,
                              void* d_out, int out_size, void* d_ws, size_t ws_size,
                              hipStream_t stream)
{
  (void)in_sizes; (void)n_in; (void)out_size;
  const float* x       = (const float*)d_in[0];
  const float* noise   = (const float*)d_in[1];
  const float* w_gate  = (const float*)d_in[2];
  const float* w_noise = (const float*)d_in[3];
  const float* W1      = (const float*)d_in[4];
  const float* b1      = (const float*)d_in[5];
  const float* W2      = (const float*)d_in[6];
  const float* b2      = (const float*)d_in[7];
  float* out = (float*)d_out;

  char* wsc = (char*)d_ws;
  int*   counts     = (int*)wsc;                          // 16
  int*   xctr       = counts + 16;                        // 16 (8 per gemm)
  int*   meta       = xctr + 16;                          // 16 (n1[8], n2[8])
  int*   tasks1     = meta + 16;                          // 8*256
  int*   tasks2     = tasks1 + 8 * 256;                   // 8*128
  int*   pair_v     = tasks2 + 8 * 128;                   // E*B
  float* gate_bk    = (float*)(pair_v + E_NUM * B_TOK);   // B*K
  float* gates_full = gate_bk + B_TOK * K_TOP;            // B*E
  float* prob_ws    = gates_full + B_TOK * E_NUM;         // B*E
  float* part       = prob_ws + B_TOK * E_NUM;            // 64*2*16
  char* big = wsc + ((((char*)(part + 64 * 2 * 16) - wsc) + 255) & ~255);
  unsigned char* x8   = (unsigned char*)big;                          // 4.2 MB
  unsigned char* Wt1  = x8 + (size_t)B_TOK * D_DIM;                   // 33.5 MB
  unsigned char* h8   = Wt1 + (size_t)E_NUM * D_DIM * H_DIM;          // 33.5 MB
  unsigned short* outw = (unsigned short*)(h8 + (size_t)B_TOK * K_TOP * H_DIM); // 33.5 MB
  unsigned char* wt2_sep = (unsigned char*)(outw + (size_t)B_TOK * K_TOP * O_DIM); // 33.5 MB

  const size_t need_big =
      (size_t)((char*)(wt2_sep + (size_t)E_NUM * H_DIM * O_DIM) - wsc);
  const int bigws = (ws_size >= need_big) ? 1 : 0;
  unsigned char* Wt2 = bigws ? wt2_sep : Wt1;

  hipMemsetAsync(counts, 0, 48 * sizeof(int), stream);    // counts + xctr + meta

  // K1: gating+convert | T1 (fp8 transpose, MLP=64)
  mega1_kernel<<<B_TOK + 2048, 256, 0, stream>>>(
      x, noise, w_gate, w_noise, counts, pair_v, gate_bk, gates_full, prob_ws,
      x8, W1, Wt1);

  prep_tasks_kernel<<<1, 64, 0, stream>>>(counts, tasks1, tasks2, meta);

  // gemm1 (256 blocks = 1/CU, KIT=8) + T2 hidden underneath if bigws
  gemm256f8_kernel<H_DIM, D_DIM, true, false, true, 256>
      <<<256 + (bigws ? 1024 : 0), 512, 0, stream>>>(
      x8, Wt1, b1, counts, pair_v, tasks1, meta, xctr,
      h8, (unsigned short*)nullptr, W2, Wt2, 256);

  if (!bigws) {   // fallback: transpose W2 into Wt1 between the gemms
    transpose_dir_kernel<<<dim3(O_DIM / 64, H_DIM / 256, E_NUM), 256, 0, stream>>>(
        W2, Wt1, H_DIM, O_DIM);
  }

  gemm256f8_kernel<O_DIM, H_DIM, false, true, false, 128><<<256, 512, 0, stream>>>(
      h8, Wt2, b2, counts, pair_v, tasks2, meta + 8, xctr + 8,
      (unsigned char*)nullptr, outw, (const float*)nullptr,
      (unsigned char*)nullptr, 256);

  // K4: softmax_y | loss partials
  mega2_kernel<<<B_TOK + 64, 256, 0, stream>>>(outw, gate_bk, out,
                                               gates_full, prob_ws, part);
  loss_final_kernel<<<1, 64, 0, stream>>>(part, out + (size_t)B_TOK * O_DIM);
}

// Round 19
// 358.037 us; speedup vs baseline: 1.4441x; 1.0106x over previous
//
#include <hip/hip_runtime.h>
#include <math.h>

#define B_TOK 4096
#define D_DIM 1024
#define H_DIM 2048
#define O_DIM 1024
#define E_NUM 16
#define K_TOP 4

#define TBM 256
#define TBN 256
#define TBK 128   // fp8 elements (= bytes) per K-tile

typedef __attribute__((ext_vector_type(4))) float f32x4;
typedef __attribute__((ext_vector_type(8))) short bf16x8;
typedef __attribute__((ext_vector_type(4))) unsigned short u16x4;
typedef __attribute__((ext_vector_type(4))) int i32x4;

__device__ __forceinline__ unsigned short f2b(float f) {
  unsigned u = __builtin_bit_cast(unsigned, f);
  u = u + 0x7FFFu + ((u >> 16) & 1u);
  return (unsigned short)(u >> 16);
}
__device__ __forceinline__ float b2f(unsigned short s) {
  return __builtin_bit_cast(float, ((unsigned)s) << 16);
}
// pack 4 f32 -> 4 fp8(e4m3, OCP on gfx950) in one int
__device__ __forceinline__ int pk4_fp8(float a, float b, float c, float d) {
  int r = __builtin_amdgcn_cvt_pk_fp8_f32(a, b, 0, false);
  r = __builtin_amdgcn_cvt_pk_fp8_f32(c, d, r, true);
  return r;
}
__device__ __forceinline__ unsigned char f2f8(float a) {
  return (unsigned char)(__builtin_amdgcn_cvt_pk_fp8_f32(a, 0.f, 0, false) & 0xff);
}
__device__ __forceinline__ void async_load16(const void* g, void* l) {
  __builtin_amdgcn_global_load_lds(
      (const __attribute__((address_space(1))) unsigned int*)g,
      (__attribute__((address_space(3))) unsigned int*)l, 16, 0, 0);
}

// ------------------------------------------- gating + x->fp8 (body) ---------
__device__ __forceinline__ void gating_body(
    int b, const float* __restrict__ x, const float* __restrict__ noise,
    const float* __restrict__ w_gate, const float* __restrict__ w_noise,
    int* __restrict__ counts, int* __restrict__ pair_v,
    float* __restrict__ gate_bk, float* __restrict__ gates_full,
    float* __restrict__ prob_ws, unsigned char* __restrict__ xb8)
{
  const int t = threadIdx.x;
  const int e = t & 15, seg = t >> 4;           // 16 segs x 64 d each
  const float* __restrict__ xr = x + (size_t)b * D_DIM;

  float pg = 0.f, pn = 0.f;
  #pragma unroll 8
  for (int j = 0; j < 64; ++j) {
    const int d = seg * 64 + j;
    const float xv = xr[d];
    pg += xv * w_gate[d * E_NUM + e];
    pn += xv * w_noise[d * E_NUM + e];
  }
  // fused x -> fp8 (row is L1/L2-hot): thread t covers elems 4t..4t+3
  {
    const f32x4 xv4 = *(const f32x4*)&xr[t * 4];
    *(int*)&xb8[(size_t)b * D_DIM + t * 4] = pk4_fp8(xv4[0], xv4[1], xv4[2], xv4[3]);
  }
  __shared__ float sg[16][16], sn[16][16];
  sg[seg][e] = pg; sn[seg][e] = pn;
  __syncthreads();

  __shared__ float s_clean[16], s_std[16], s_noisy[16];
  if (t < 32) {
    const int which = t >> 4, ee = t & 15;
    float s = 0.f;
    #pragma unroll
    for (int i = 0; i < 16; ++i) s += which ? sn[i][ee] : sg[i][ee];
    if (which == 0) s_clean[ee] = s;
    else {
      const float sp = (s > 0.f) ? (s + log1pf(expf(-s))) : log1pf(expf(s));
      s_std[ee] = sp + 0.01f;
    }
  }
  __syncthreads();
  if (t < 16) s_noisy[t] = s_clean[t] + noise[(size_t)b * E_NUM + t] * s_std[t];
  __syncthreads();

  __shared__ float s_top[5];
  __shared__ int   s_idx[4];
  __shared__ float s_gates[4];
  if (t == 0) {
    float v[16];
    #pragma unroll
    for (int i = 0; i < 16; ++i) v[i] = s_noisy[i];
    unsigned mask = 0;
    float tv[5]; int ti[5];
    #pragma unroll
    for (int k = 0; k < 5; ++k) {
      float best = -3.4e38f; int bi = 0;
      #pragma unroll
      for (int i = 0; i < 16; ++i) {
        const bool ok = !((mask >> i) & 1u) && (v[i] > best);
        best = ok ? v[i] : best;
        bi   = ok ? i    : bi;
      }
      mask |= (1u << bi);
      tv[k] = best; ti[k] = bi;
    }
    const float m = tv[0];
    float ex[4], se = 0.f;
    #pragma unroll
    for (int k = 0; k < 4; ++k) { ex[k] = expf(tv[k] - m); se += ex[k]; }
    #pragma unroll
    for (int k = 0; k < 4; ++k) s_gates[k] = ex[k] / se;
    #pragma unroll
    for (int k = 0; k < 5; ++k) s_top[k] = tv[k];
    #pragma unroll
    for (int k = 0; k < 4; ++k) s_idx[k] = ti[k];
  }
  __syncthreads();

  if (t < 16) gates_full[(size_t)b * E_NUM + t] = 0.f;
  __syncthreads();
  if (t < 4) {
    const int ee = s_idx[t];
    const float g = s_gates[t];
    gate_bk[b * K_TOP + t] = g;
    gates_full[(size_t)b * E_NUM + ee] = g;
    const int slot = atomicAdd(&counts[ee], 1);
    pair_v[ee * B_TOK + slot] = b * K_TOP + t;     // h-row index = b*4 + rank
  }
  if (t < 16) {
    const float thr_in = s_top[4], thr_out = s_top[3];
    const float thr = (s_noisy[t] > thr_in) ? thr_in : thr_out;
    const float z = (s_clean[t] - thr) / s_std[t];
    prob_ws[(size_t)b * E_NUM + t] = 0.5f * (1.f + erff(z * 0.70710678118654752f));
  }
}

// --------------- direct transpose fp32 -> fp8, 64B-per-lane writes ----------
__device__ __forceinline__ void transpose64_f8(
    const float* __restrict__ in, unsigned char* __restrict__ out,
    int R, int C, int e, int n, int k0)
{
  const float* __restrict__ ip = in + (size_t)e * R * C + (size_t)k0 * C + n;
  unsigned char* __restrict__ op = out + (size_t)e * R * C + (size_t)n * R + k0;
  float v[64];
  #pragma unroll
  for (int q = 0; q < 64; ++q) v[q] = ip[(size_t)q * C];
  __builtin_amdgcn_sched_barrier(0);        // issue all 64 loads first
  #pragma unroll
  for (int g4 = 0; g4 < 4; ++g4) {
    i32x4 o;
    #pragma unroll
    for (int q = 0; q < 4; ++q) {
      const int s = g4 * 16 + q * 4;
      o[q] = pk4_fp8(v[s], v[s + 1], v[s + 2], v[s + 3]);
    }
    *(i32x4*)&op[g4 * 16] = o;
  }
}

// --------------------------------------------------------------- mega K1 ----
// gating+convert (4096) | T1: W1->Wt1 (2048 blocks, 64n x 256k tiles)
__global__ __launch_bounds__(256) void mega1_kernel(
    const float* __restrict__ x, const float* __restrict__ noise,
    const float* __restrict__ w_gate, const float* __restrict__ w_noise,
    int* __restrict__ counts, int* __restrict__ pair_v,
    float* __restrict__ gate_bk, float* __restrict__ gates_full,
    float* __restrict__ prob_ws, unsigned char* __restrict__ xb8,
    const float* __restrict__ W1, unsigned char* __restrict__ Wt1)
{
  int bid = blockIdx.x;
  if (bid < B_TOK) {
    gating_body(bid, x, noise, w_gate, w_noise, counts, pair_v,
                gate_bk, gates_full, prob_ws, xb8);
    return;
  }
  bid -= B_TOK;      // T1: R=D(k)=1024, C=H(n)=2048: nb 32 x kb 4 x e 16
  const int nb = bid & 31, kb = (bid >> 5) & 3, e = bid >> 7;
  const int w = threadIdx.x >> 6, lane = threadIdx.x & 63;
  transpose64_f8(W1, Wt1, D_DIM, H_DIM, e, nb * 64 + lane, kb * 256 + w * 64);
}

// standalone T2 (fallback path, between gemms): grid (16 nb, 8 kb, 16 e)
__global__ __launch_bounds__(256) void transpose_dir_kernel(
    const float* __restrict__ in, unsigned char* __restrict__ out,
    int R, int C)
{
  const int w = threadIdx.x >> 6, lane = threadIdx.x & 63;
  transpose64_f8(in, out, R, C, blockIdx.z, blockIdx.x * 64 + lane,
                 blockIdx.y * 256 + w * 64);
}

// -------------------------------------------------------------- prep tasks --
// Per-XCD queues; experts {x, x+8} -> XCD x.  Order (e, m, nb).
__global__ void prep_tasks_kernel(const int* __restrict__ counts,
                                  int* __restrict__ tasks1,   // [8][256]
                                  int* __restrict__ tasks2,   // [8][128]
                                  int* __restrict__ meta)     // n1[8], n2[8]
{
  const int xx = threadIdx.x;
  if (xx < 8) {
    int k1 = 0, k2 = 0;
    for (int hh = 0; hh < 2; ++hh) {
      const int e = xx + hh * 8;
      const int mb = (counts[e] + TBM - 1) / TBM;
      for (int m = 0; m < mb; ++m)
        for (int nb = 0; nb < H_DIM / TBN; ++nb)
          tasks1[xx * 256 + (k1++)] = (e << 16) | (m << 8) | nb;
      for (int m = 0; m < mb; ++m)
        for (int nb = 0; nb < O_DIM / TBN; ++nb)
          tasks2[xx * 128 + (k2++)] = (e << 16) | (m << 8) | nb;
    }
    meta[xx] = k1;
    meta[8 + xx] = k2;
  }
}

// ------------------- one 256x256 fp8 GEMM tile (R17 inner loop) -------------
// TBK=128B, KIT = KDIM/128; staging: R13-proven 8-chunk involution
// gc=(t&7)^((t>>3)&7), LDS linear; read b64: cI = (ks*2+(gA>>1))^(row&7).
template<int NDIM, int KDIM, bool RELU, bool APAIR, bool OUT8>
__device__ __forceinline__ void gemm_tile_f8(
    int tk,
    const unsigned char* __restrict__ A,
    const unsigned char* __restrict__ Bt,
    const float* __restrict__ biasE,
    const int* __restrict__ counts, const int* __restrict__ pair_v,
    unsigned char* __restrict__ Out8, unsigned short* __restrict__ Out16,
    unsigned char* As, unsigned char* Bs)
{
  const int t = threadIdx.x;
  const int w = t >> 6, l = t & 63;
  const int gc = (t & 7) ^ ((t >> 3) & 7);
  const int sr = t >> 3;
  const int wr = w >> 2, wc = w & 3;
  const int lr = l & 15, gA = l >> 4;

  const int e  = tk >> 16;
  const int m0 = ((tk >> 8) & 255) * TBM;
  const int n0 = (tk & 255) * TBN;
  const int cnt = counts[e];
  const int* __restrict__ plist = pair_v + e * B_TOK;

  const unsigned char* aG[4];
  const unsigned char* bG[4];
  #pragma unroll
  for (int i = 0; i < 4; ++i) {
    const int r = i * 64 + sr;
    const int pr = (m0 + r < cnt) ? plist[m0 + r] : -1;
    const size_t tok = (size_t)(pr < 0 ? 0 : (APAIR ? pr : (pr >> 2)));
    aG[i] = A + tok * KDIM + gc * 16;
    bG[i] = Bt + ((size_t)e * NDIM + n0 + r) * KDIM + gc * 16;
  }

#define STAGE(bufi, kt) do {                                              \
    const int ko_ = (kt) * TBK;                                           \
    _Pragma("unroll")                                                     \
    for (int i_ = 0; i_ < 4; ++i_) {                                      \
      async_load16(aG[i_] + ko_, As + (bufi) * 32768 + i_ * 8192 + w * 1024); \
      async_load16(bG[i_] + ko_, Bs + (bufi) * 32768 + i_ * 8192 + w * 1024); \
    }                                                                     \
  } while (0)

  f32x4 acc[8][4];
  #pragma unroll
  for (int i = 0; i < 8; ++i)
    #pragma unroll
    for (int j = 0; j < 4; ++j)
      acc[i][j] = (f32x4){0.f, 0.f, 0.f, 0.f};

  STAGE(0, 0);
  __syncthreads();                       // drains vmcnt(0): buf0 ready

  int buf = 0;
  constexpr int KIT = KDIM / TBK;        // 8 or 16
  for (int kt = 0; kt < KIT; ++kt) {
    if (kt + 1 < KIT) STAGE(buf ^ 1, kt + 1);
    #pragma unroll
    for (int ks = 0; ks < 4; ++ks) {
      long a8[8]; long b8[4];
      #pragma unroll
      for (int i = 0; i < 8; ++i) {
        const int ra = wr * 128 + i * 16 + lr;
        const int cI = (ks * 2 + (gA >> 1)) ^ (ra & 7);
        a8[i] = *(const long*)&As[buf * 32768 + ra * 128 + cI * 16 + (gA & 1) * 8];
      }
      #pragma unroll
      for (int j = 0; j < 4; ++j) {
        const int rb = wc * 64 + j * 16 + lr;
        const int cI = (ks * 2 + (gA >> 1)) ^ (rb & 7);
        b8[j] = *(const long*)&Bs[buf * 32768 + rb * 128 + cI * 16 + (gA & 1) * 8];
      }
      #pragma unroll
      for (int i = 0; i < 8; ++i)
        #pragma unroll
        for (int j = 0; j < 4; ++j)
          acc[i][j] = __builtin_amdgcn_mfma_f32_16x16x32_fp8_fp8(
              a8[i], b8[j], acc[i][j], 0, 0, 0);
    }
    __syncthreads();                     // waits vmcnt(0): next buf landed
    buf ^= 1;
  }
#undef STAGE

  const float* __restrict__ bias = biasE + (size_t)e * NDIM + n0;
  #pragma unroll
  for (int i = 0; i < 8; ++i) {
    #pragma unroll
    for (int q2 = 0; q2 < 4; ++q2) {
      const int rl = wr * 128 + i * 16 + gA * 4 + q2;
      if (m0 + rl < cnt) {
        const int pr = plist[m0 + rl];
        #pragma unroll
        for (int j = 0; j < 4; ++j) {
          const int col = wc * 64 + j * 16 + lr;
          float vv = acc[i][j][q2] + bias[col];
          if (RELU) vv = vv > 0.f ? vv : 0.f;
          if (OUT8) Out8[(size_t)pr * NDIM + n0 + col] = f2f8(vv);
          else      Out16[(size_t)pr * NDIM + n0 + col] = f2b(vv);
        }
      }
    }
  }
}

// ------- gemm1 + T2 fused (two PHASES, no inter-block waits — safe) ---------
// 256 persistent blocks. Phase 1: drain gemm1 queues (work-steal). Phase 2:
// blocks that run out of gemm1 work pull T2 transpose subtiles — T2 fills the
// tail idle of gemm1's 3-tile quantization. gemm2 (next launch) is ordered by
// the kernel completion boundary. No block ever waits on another block.
__global__ __launch_bounds__(512, 1) void gemm1_t2_kernel(
    const unsigned char* __restrict__ x8,
    const unsigned char* __restrict__ Wt1, const float* __restrict__ b1,
    unsigned char* __restrict__ h8,
    const float* __restrict__ W2, unsigned char* __restrict__ Wt2,
    const int* __restrict__ counts, const int* __restrict__ pair_v,
    const int* __restrict__ tasks1, const int* __restrict__ n1,
    int* __restrict__ ctr1, int* __restrict__ t2ctr, int do_t2)
{
  __shared__ __align__(16) unsigned char As[2 * TBM * TBK];   // 64 KB
  __shared__ __align__(16) unsigned char Bs[2 * TBN * TBK];   // 64 KB
  __shared__ int s_task;

  const int t = threadIdx.x;
  const int xcd = blockIdx.x & 7;

  // ---- phase 1: gemm1 (h8 = relu(x8 @ W1t + b1), fp8 out) ----
  for (int v = 0; v < 8; ++v) {
    const int q = (xcd + v) & 7;
    const int nt = n1[q];
    const int* __restrict__ tl = tasks1 + q * 256;
    for (;;) {
      if (t == 0) s_task = atomicAdd(&ctr1[q], 1);
      __syncthreads();
      const int task = s_task;
      if (task >= nt) break;
      gemm_tile_f8<H_DIM, D_DIM, true, false, true>(
          tl[task], x8, Wt1, b1, counts, pair_v, h8,
          (unsigned short*)nullptr, As, Bs);
      __syncthreads();
    }
  }

  // ---- phase 2: T2 (W2 -> Wt2 fp8 transpose), 1024 subtiles ----
  if (!do_t2) return;
  for (;;) {
    if (t == 0) s_task = atomicAdd(t2ctr, 1);
    __syncthreads();
    const int idx = s_task;
    if (idx >= 1024) break;
    const int nb = idx & 15, kb = (idx >> 4) & 3, e2 = idx >> 6;
    const int w = t >> 6, l = t & 63;
    transpose64_f8(W2, Wt2, H_DIM, O_DIM, e2, nb * 64 + l, kb * 512 + w * 64);
    __syncthreads();
  }
}

// ---------------- standalone gemm (gemm2 + fallback paths) ------------------
template<int NDIM, int KDIM, bool RELU, bool APAIR, bool OUT8, int QSTRIDE>
__global__ __launch_bounds__(512, 1) void gemm256f8_kernel(
    const unsigned char* __restrict__ A,
    const unsigned char* __restrict__ Bt,
    const float* __restrict__ biasE,
    const int* __restrict__ counts, const int* __restrict__ pair_v,
    const int* __restrict__ tasks, const int* __restrict__ ntasks,
    int* __restrict__ xctr,
    unsigned char* __restrict__ Out8, unsigned short* __restrict__ Out16)
{
  __shared__ __align__(16) unsigned char As[2 * TBM * TBK];
  __shared__ __align__(16) unsigned char Bs[2 * TBN * TBK];
  __shared__ int s_task;
  const int t = threadIdx.x;
  const int xcd = blockIdx.x & 7;
  for (int v = 0; v < 8; ++v) {
    const int q = (xcd + v) & 7;
    const int nt = ntasks[q];
    const int* __restrict__ tl = tasks + q * QSTRIDE;
    for (;;) {
      if (t == 0) s_task = atomicAdd(&xctr[q], 1);
      __syncthreads();
      const int task = s_task;
      if (task >= nt) break;
      gemm_tile_f8<NDIM, KDIM, RELU, APAIR, OUT8>(
          tl[task], A, Bt, biasE, counts, pair_v, Out8, Out16, As, Bs);
      __syncthreads();
    }
  }
}

// ------------------------------------------------------- softmax+y (body) ---
__device__ __forceinline__ void softmax_body(
    int b, const unsigned short* __restrict__ outw,
    const float* __restrict__ gate_bk, float* __restrict__ y)
{
  const int t = threadIdx.x;
  const int w = t >> 6, l = t & 63;
  __shared__ float acc_s[4][O_DIM];

  const unsigned short* __restrict__ row = outw + (size_t)(b * K_TOP + w) * O_DIM;
  float v[16];
  const bf16x8 r0 = *(const bf16x8*)&row[l * 16];
  const bf16x8 r1 = *(const bf16x8*)&row[l * 16 + 8];
  #pragma unroll
  for (int i = 0; i < 8; ++i) {
    v[i]     = b2f((unsigned short)r0[i]);
    v[i + 8] = b2f((unsigned short)r1[i]);
  }
  float mx = v[0];
  #pragma unroll
  for (int i = 1; i < 16; ++i) mx = fmaxf(mx, v[i]);
  #pragma unroll
  for (int off = 32; off >= 1; off >>= 1) mx = fmaxf(mx, __shfl_xor(mx, off, 64));
  float ex[16], ps = 0.f;
  #pragma unroll
  for (int i = 0; i < 16; ++i) { ex[i] = expf(v[i] - mx); ps += ex[i]; }
  #pragma unroll
  for (int off = 32; off >= 1; off >>= 1) ps += __shfl_xor(ps, off, 64);
  const float g = gate_bk[b * K_TOP + w];
  const float inv = 1.f / ps;
  #pragma unroll
  for (int i = 0; i < 16; ++i) acc_s[w][l * 16 + i] = g * expf(ex[i] * inv);
  __syncthreads();
  #pragma unroll
  for (int i = 0; i < 4; ++i) {
    const int col = t + i * 256;
    y[(size_t)b * O_DIM + col] =
        acc_s[0][col] + acc_s[1][col] + acc_s[2][col] + acc_s[3][col];
  }
}

// ------------------------------------------------------- loss part (body) ---
__device__ __forceinline__ void losspart_body(
    int blk, const float* __restrict__ gates_full,
    const float* __restrict__ prob_ws, float* __restrict__ part)
{
  const int t = threadIdx.x;
  const int e = t & 15, seg = t >> 4;
  float si = 0.f, sl = 0.f;
  #pragma unroll
  for (int j = 0; j < 4; ++j) {
    const int b = blk * 64 + seg * 4 + j;
    si += gates_full[(size_t)b * E_NUM + e];
    sl += prob_ws[(size_t)b * E_NUM + e];
  }
  __shared__ float li[16][16], ll[16][16];
  li[seg][e] = si; ll[seg][e] = sl;
  __syncthreads();
  if (t < 32) {
    const int which = t >> 4, ee = t & 15;
    float s = 0.f;
    #pragma unroll
    for (int i = 0; i < 16; ++i) s += which ? ll[i][ee] : li[i][ee];
    part[(blk * 2 + which) * 16 + ee] = s;
  }
}

// --------------------------------------------------------------- mega K4 ----
__global__ __launch_bounds__(256) void mega2_kernel(
    const unsigned short* __restrict__ outw, const float* __restrict__ gate_bk,
    float* __restrict__ y, const float* __restrict__ gates_full,
    const float* __restrict__ prob_ws, float* __restrict__ part)
{
  const int bid = blockIdx.x;
  if (bid < B_TOK) softmax_body(bid, outw, gate_bk, y);
  else             losspart_body(bid - B_TOK, gates_full, prob_ws, part);
}

__global__ __launch_bounds__(64) void loss_final_kernel(
    const float* __restrict__ part, float* __restrict__ out_loss)
{
  const int t = threadIdx.x;
  __shared__ float fi[16], fl[16];
  if (t < 32) {
    const int which = t >> 4, e = t & 15;
    float s = 0.f;
    for (int i = 0; i < 64; ++i) s += part[(i * 2 + which) * 16 + e];
    if (which) fl[e] = s; else fi[e] = s;
  }
  __syncthreads();
  if (t == 0) {
    float mi = 0.f, ml = 0.f;
    #pragma unroll
    for (int e = 0; e < 16; ++e) { mi += fi[e]; ml += fl[e]; }
    mi *= (1.f / 16.f); ml *= (1.f / 16.f);
    float vi = 0.f, vl = 0.f;
    #pragma unroll
    for (int e = 0; e < 16; ++e) {
      const float di = fi[e] - mi, dl = fl[e] - ml;
      vi += di * di; vl += dl * dl;
    }
    vi *= (1.f / 15.f); vl *= (1.f / 15.f);
    out_loss[0] = (vi / (mi * mi + 1e-10f) + vl / (ml * ml + 1e-10f)) * 0.01f;
  }
}

// ---------------------------------------------------------------- launch ----
extern "C" void kernel_launch(void* const* d_in, const int* in_sizes, int n_in,
                              void* d_out, int out_size, void* d_ws, size_t ws_size,
                              hipStream_t stream)
{
  (void)in_sizes; (void)n_in; (void)out_size;
  const float* x       = (const float*)d_in[0];
  const float* noise   = (const float*)d_in[1];
  const float* w_gate  = (const float*)d_in[2];
  const float* w_noise = (const float*)d_in[3];
  const float* W1      = (const float*)d_in[4];
  const float* b1      = (const float*)d_in[5];
  const float* W2      = (const float*)d_in[6];
  const float* b2      = (const float*)d_in[7];
  float* out = (float*)d_out;

  char* wsc = (char*)d_ws;
  int*   counts     = (int*)wsc;                          // 16
  int*   xctr       = counts + 16;                        // 16 (ctr1[8], ctr2[8])
  int*   meta       = xctr + 16;                          // 16 (n1[8], n2[8])
  int*   sync2      = meta + 16;                          // 2 (t2ctr, spare)
  int*   hdone      = sync2 + 2;                          // 256 (unused, layout keep)
  int*   tasks1     = hdone + 256;                        // 8*256
  int*   tasks2     = tasks1 + 8 * 256;                   // 8*128
  int*   pair_v     = tasks2 + 8 * 128;                   // E*B
  float* gate_bk    = (float*)(pair_v + E_NUM * B_TOK);   // B*K
  float* gates_full = gate_bk + B_TOK * K_TOP;            // B*E
  float* prob_ws    = gates_full + B_TOK * E_NUM;         // B*E
  float* part       = prob_ws + B_TOK * E_NUM;            // 64*2*16
  char* big = wsc + ((((char*)(part + 64 * 2 * 16) - wsc) + 255) & ~255);
  unsigned char* x8   = (unsigned char*)big;                          // 4.2 MB
  unsigned char* Wt1  = x8 + (size_t)B_TOK * D_DIM;                   // 33.5 MB
  unsigned char* h8   = Wt1 + (size_t)E_NUM * D_DIM * H_DIM;          // 33.5 MB
  unsigned short* outw = (unsigned short*)(h8 + (size_t)B_TOK * K_TOP * H_DIM); // 33.5 MB
  unsigned char* wt2_sep = (unsigned char*)(outw + (size_t)B_TOK * K_TOP * O_DIM); // 33.5 MB

  const size_t need_big =
      (size_t)((char*)(wt2_sep + (size_t)E_NUM * H_DIM * O_DIM) - wsc);
  const int bigws = (ws_size >= need_big) ? 1 : 0;
  unsigned char* Wt2 = bigws ? wt2_sep : Wt1;

  hipMemsetAsync(counts, 0, (16 + 16 + 16 + 2 + 256) * sizeof(int), stream);

  // K1: gating+convert | T1 (fp8 transpose, MLP=64)
  mega1_kernel<<<B_TOK + 2048, 256, 0, stream>>>(
      x, noise, w_gate, w_noise, counts, pair_v, gate_bk, gates_full, prob_ws,
      x8, W1, Wt1);

  prep_tasks_kernel<<<1, 64, 0, stream>>>(counts, tasks1, tasks2, meta);

  if (bigws) {
    // gemm1 with T2 phase filling its tail idle (no inter-block waits)
    gemm1_t2_kernel<<<256, 512, 0, stream>>>(
        x8, Wt1, b1, h8, W2, Wt2, counts, pair_v, tasks1, meta, xctr, sync2, 1);
    gemm256f8_kernel<O_DIM, H_DIM, false, true, false, 128><<<256, 512, 0, stream>>>(
        h8, Wt2, b2, counts, pair_v, tasks2, meta + 8, xctr + 8,
        (unsigned char*)nullptr, outw);
  } else {
    gemm256f8_kernel<H_DIM, D_DIM, true, false, true, 256><<<256, 512, 0, stream>>>(
        x8, Wt1, b1, counts, pair_v, tasks1, meta, xctr,
        h8, (unsigned short*)nullptr);
    transpose_dir_kernel<<<dim3(O_DIM / 64, H_DIM / 256, E_NUM), 256, 0, stream>>>(
        W2, Wt1, H_DIM, O_DIM);
    gemm256f8_kernel<O_DIM, H_DIM, false, true, false, 128><<<256, 512, 0, stream>>>(
        h8, Wt1, b2, counts, pair_v, tasks2, meta + 8, xctr + 8,
        (unsigned char*)nullptr, outw);
  }

  // K4: softmax_y | loss partials
  mega2_kernel<<<B_TOK + 64, 256, 0, stream>>>(outw, gate_bk, out,
                                               gates_full, prob_ws, part);
  loss_final_kernel<<<1, 64, 0, stream>>>(part, out + (size_t)B_TOK * O_DIM);
}